// Round 5
// baseline (303.054 us; speedup 1.0000x reference)
//
#include <hip/hip_runtime.h>
#include <hip/hip_fp16.h>

#define NPTS 100000
#define NB 500
#define KNN 100
#define KPN 15
#define C1 128
#define C2 1024
#define C3 512
#define C4 256

// ---- L-inf kNN grid parameters
#define G 64
#define NCELLS (G * G * G)
#define GB 5.0f
#define GINVH ((float)G / (2.f * GB))  // 6.4 cells per unit
#define CAND_CAP 2048

typedef _Float16 half8 __attribute__((ext_vector_type(8)));
typedef float f32x4 __attribute__((ext_vector_type(4)));

// ------------------------------------------------- grid helpers
__device__ __forceinline__ int cell_coord(float x) {
  int c = (int)floorf((x + GB) * GINVH);
  return min(max(c, 0), G - 1);
}
__device__ __forceinline__ int cell_of(float x, float y, float z) {
  return (cell_coord(x) << 12) | (cell_coord(y) << 6) | cell_coord(z);
}

// ------------------------------------ prep: gather + converts + grid hist
__global__ __launch_bounds__(256) void prep_kernel(
    const float* __restrict__ pts, const float* __restrict__ normal,
    const int* __restrict__ index, const float* __restrict__ w1,
    const float* __restrict__ kpw, float* __restrict__ sel,
    float* __restrict__ out2, __half* __restrict__ wh,
    __half* __restrict__ kpwT_hi, __half* __restrict__ kpwT_lo,
    unsigned* __restrict__ cnt) {
  int i = blockIdx.x * 256 + threadIdx.x;
  if (i < NB) {
    int ix = index[i];
    sel[i * 3 + 0] = pts[3 * ix + 0];
    sel[i * 3 + 1] = pts[3 * ix + 1];
    sel[i * 3 + 2] = pts[3 * ix + 2];
    out2[i * 3 + 0] = normal[3 * ix + 0];
    out2[i * 3 + 1] = normal[3 * ix + 1];
    out2[i * 3 + 2] = normal[3 * ix + 2];
  }
  if (i < C2 * C1) wh[i] = __float2half(w1[i]);
  if (i < 128 * 64) {
    int o = i >> 6, j = i & 63;
    float v = (j < 45) ? kpw[j * 128 + o] : 0.f;
    __half hi = __float2half_rn(v);
    kpwT_hi[i] = hi;
    kpwT_lo[i] = __float2half_rn(v - __half2float(hi));
  }
  if (i < NPTS)
    atomicAdd(&cnt[cell_of(pts[3 * i], pts[3 * i + 1], pts[3 * i + 2])], 1u);
}

// ------------------------------------------------- grid scan (3 stages)
__global__ __launch_bounds__(256) void grid_scan1_kernel(
    const unsigned* __restrict__ cnt, unsigned* __restrict__ cursor,
    unsigned* __restrict__ chunktot) {
  const int tid = threadIdx.x;
  int base = blockIdx.x * 1024 + tid * 4;
  unsigned c0 = cnt[base], c1 = cnt[base + 1], c2 = cnt[base + 2],
           c3 = cnt[base + 3];
  unsigned tot = c0 + c1 + c2 + c3;
  __shared__ unsigned sb[256];
  sb[tid] = tot;
  __syncthreads();
  for (int off = 1; off < 256; off <<= 1) {
    unsigned add = (tid >= off) ? sb[tid - off] : 0u;
    __syncthreads();
    sb[tid] += add;
    __syncthreads();
  }
  unsigned excl = sb[tid] - tot;
  cursor[base] = excl;
  cursor[base + 1] = excl + c0;
  cursor[base + 2] = excl + c0 + c1;
  cursor[base + 3] = excl + c0 + c1 + c2;
  if (tid == 255) chunktot[blockIdx.x] = sb[255];
}

__global__ __launch_bounds__(256) void grid_scan2_kernel(
    const unsigned* __restrict__ chunktot, unsigned* __restrict__ chunkoff) {
  const int tid = threadIdx.x;
  unsigned v = chunktot[tid];
  __shared__ unsigned sb[256];
  sb[tid] = v;
  __syncthreads();
  for (int off = 1; off < 256; off <<= 1) {
    unsigned add = (tid >= off) ? sb[tid - off] : 0u;
    __syncthreads();
    sb[tid] += add;
    __syncthreads();
  }
  chunkoff[tid] = sb[tid] - v;
}

__global__ __launch_bounds__(256) void grid_scan3_kernel(
    unsigned* __restrict__ cursor, const unsigned* __restrict__ chunkoff) {
  unsigned off = chunkoff[blockIdx.x];
  int base = blockIdx.x * 1024 + threadIdx.x * 4;
#pragma unroll
  for (int j = 0; j < 4; ++j) cursor[base + j] += off;
}

// scatter: cursor turns into per-cell END offsets; begin = end - cnt
__global__ __launch_bounds__(256) void grid_scatter_kernel(
    const float* __restrict__ pts, unsigned* __restrict__ cursor,
    float4* __restrict__ sorted) {
  int i = blockIdx.x * 256 + threadIdx.x;
  if (i >= NPTS) return;
  float x = pts[3 * i], y = pts[3 * i + 1], z = pts[3 * i + 2];
  unsigned pos = atomicAdd(&cursor[cell_of(x, y, z)], 1u);
  sorted[pos] = make_float4(x, y, z, __int_as_float(i));
}

// ---------------------------------------------------------------- kNN v6
// Grid-accelerated exact L-inf kNN. Phase A: shell-incremental cube count
// (only newly-added shell cells loaded each expansion). Phase B: per-cell
// batched candidate collection. Histogram select -> exact cover cube ->
// exact rank-select (ties by index; downstream order-invariant).
__device__ __forceinline__ unsigned linf_bits(float px, float py, float pz,
                                              float sx, float sy, float sz) {
  float dx = fabsf(px - sx), dy = fabsf(py - sy), dz = fabsf(pz - sz);
  return __float_as_uint(fmaxf(fmaxf(dx, dy), dz));
}

__global__ __launch_bounds__(256) void knn_kernel(
    const float4* __restrict__ sorted, const unsigned* __restrict__ cnt,
    const unsigned* __restrict__ cursor,  // per-cell end offsets
    const float* __restrict__ sel, int* __restrict__ nbr) {
  const int b = blockIdx.x;
  const int tid = threadIdx.x;
  __shared__ unsigned cbits[CAND_CAP];
  __shared__ int cidx[CAND_CAP];
  __shared__ unsigned hist[4096];
  __shared__ unsigned scanbuf[256];
  __shared__ int s_total, s_m, s_mc, s_chunk;
  __shared__ unsigned s_excl, s_bub;

  const float qx = sel[b * 3 + 0], qy = sel[b * 3 + 1], qz = sel[b * 3 + 2];
  const int qcx = cell_coord(qx), qcy = cell_coord(qy), qcz = cell_coord(qz);

  // ---------------- Phase A: expand cube until >=KNN (shell-incremental)
  if (tid == 0) s_total = 0;
  __syncthreads();
  int s = 1;
  int pxlo = 1, pxhi = 0, pylo = 1, pyhi = 0, pzlo = 1, pzhi = 0;  // empty
  int xlo, xhi, ylo, yhi, zlo, zhi;
  for (;;) {
    xlo = max(qcx - s, 0); xhi = min(qcx + s, G - 1);
    ylo = max(qcy - s, 0); yhi = min(qcy + s, G - 1);
    zlo = max(qcz - s, 0); zhi = min(qcz + s, G - 1);
    int nx = xhi - xlo + 1, ny = yhi - ylo + 1, nz = zhi - zlo + 1;
    int ncell = nx * ny * nz;
    unsigned local = 0;
    for (int ci = tid; ci < ncell; ci += 256) {
      int cz = ci % nz;
      int r = ci / nz;
      int cy = r % ny;
      int cx = r / ny;
      int ax = xlo + cx, ay = ylo + cy, az = zlo + cz;
      if (ax >= pxlo && ax <= pxhi && ay >= pylo && ay <= pyhi &&
          az >= pzlo && az <= pzhi)
        continue;  // interior (already counted)
      local += cnt[(ax << 12) | (ay << 6) | az];
    }
#pragma unroll
    for (int off = 32; off; off >>= 1) local += __shfl_down(local, off);
    if ((tid & 63) == 0) atomicAdd(&s_total, (int)local);
    __syncthreads();
    if (s_total >= KNN || (xlo == 0 && ylo == 0 && zlo == 0 && xhi == G - 1 &&
                           yhi == G - 1 && zhi == G - 1))
      break;
    pxlo = xlo; pxhi = xhi; pylo = ylo; pyhi = yhi; pzlo = zlo; pzhi = zhi;
    ++s;
    __syncthreads();
  }

  // ---------------- Phase B: collect cube points (per-cell batched slots)
  if (tid == 0) s_m = 0;
  __syncthreads();
  {
    int nx = xhi - xlo + 1, ny = yhi - ylo + 1, nz = zhi - zlo + 1;
    int ncell = nx * ny * nz;
    for (int ci = tid; ci < ncell; ci += 256) {
      int cz = ci % nz;
      int r = ci / nz;
      int cy = r % ny;
      int cx = r / ny;
      int cell = ((xlo + cx) << 12) | ((ylo + cy) << 6) | (zlo + cz);
      unsigned end = cursor[cell];
      unsigned beg = end - cnt[cell];
      int k = (int)(end - beg);
      if (k > 0) {
        int e0 = atomicAdd(&s_m, k);
        for (unsigned p = beg; p < end; ++p, ++e0) {
          if (e0 < CAND_CAP) {
            float4 f = sorted[p];
            cbits[e0] = linf_bits(f.x, f.y, f.z, qx, qy, qz);
            cidx[e0] = __float_as_int(f.w);
          }
        }
      }
    }
  }
  __syncthreads();
  int m = s_m < CAND_CAP ? s_m : CAND_CAP;

  // ---------------- histogram select: upper bound on 100th distance
  for (int j = tid; j < 4096; j += 256) hist[j] = 0;
  __syncthreads();
  for (int e = tid; e < m; e += 256) atomicAdd(&hist[cbits[e] >> 19], 1u);
  __syncthreads();
  unsigned csum = 0;
  {
    int c0 = tid * 16;
#pragma unroll
    for (int j = 0; j < 16; ++j) csum += hist[c0 + j];
  }
  scanbuf[tid] = csum;
  __syncthreads();
  for (int off = 1; off < 256; off <<= 1) {
    unsigned add = (tid >= off) ? scanbuf[tid - off] : 0u;
    __syncthreads();
    scanbuf[tid] += add;
    __syncthreads();
  }
  {
    unsigned incl = scanbuf[tid], excl = incl - csum;
    if (excl < KNN && KNN <= incl) {
      s_chunk = tid;
      s_excl = excl;
    }
  }
  __syncthreads();
  if (tid == 0) {
    unsigned cum = s_excl;
    int bin = s_chunk * 16;
    while (cum + hist[bin] < KNN) {
      cum += hist[bin];
      ++bin;
    }
    s_bub = (unsigned)(bin + 1) << 19;  // exclusive upper bound on bits
  }
  __syncthreads();

  // ---------------- Phase C: exact cover cube, filter bits < bound
  const unsigned bub = s_bub;
  const float dub = __uint_as_float(bub);
  if (tid == 0) s_mc = 0;
  __syncthreads();
  {
    int xlo2 = min(max((int)floorf((qx - dub + GB) * GINVH), 0), G - 1);
    int xhi2 = min(max((int)floorf((qx + dub + GB) * GINVH), 0), G - 1);
    int ylo2 = min(max((int)floorf((qy - dub + GB) * GINVH), 0), G - 1);
    int yhi2 = min(max((int)floorf((qy + dub + GB) * GINVH), 0), G - 1);
    int zlo2 = min(max((int)floorf((qz - dub + GB) * GINVH), 0), G - 1);
    int zhi2 = min(max((int)floorf((qz + dub + GB) * GINVH), 0), G - 1);
    int nx = xhi2 - xlo2 + 1, ny = yhi2 - ylo2 + 1, nz = zhi2 - zlo2 + 1;
    int ncell = nx * ny * nz;
    for (int ci = tid; ci < ncell; ci += 256) {
      int cz = ci % nz;
      int r = ci / nz;
      int cy = r % ny;
      int cx = r / ny;
      int cell = ((xlo2 + cx) << 12) | ((ylo2 + cy) << 6) | (zlo2 + cz);
      unsigned end = cursor[cell];
      unsigned beg = end - cnt[cell];
      for (unsigned p = beg; p < end; ++p) {
        float4 f = sorted[p];
        unsigned bits = linf_bits(f.x, f.y, f.z, qx, qy, qz);
        if (bits < bub) {
          int e = atomicAdd(&s_mc, 1);
          if (e < CAND_CAP) {
            cbits[e] = bits;
            cidx[e] = __float_as_int(f.w);
          }
        }
      }
    }
  }
  __syncthreads();
  int mc = s_mc < CAND_CAP ? s_mc : CAND_CAP;

  // ---------------- exact rank-select (ties by original index, stable)
  for (int c = tid; c < mc; c += 256) {
    unsigned bc = cbits[c];
    int ic = cidx[c];
    int rank = 0;
    for (int j = 0; j < mc; ++j) {
      unsigned bj = cbits[j];
      rank += (bj < bc || (bj == bc && cidx[j] < ic)) ? 1 : 0;
    }
    if (rank < KNN) nbr[b * KNN + rank] = ic;
  }
}

// ---------------------------- KPConv + conv1 FUSED (f16 MFMA, 8 waves)
// 512 threads: wave w owns one 16-col tile -> acc[7]; 16 waves/CU at
// 2 blocks/CU for 2x latency hiding vs the 4-wave version.
__global__ __launch_bounds__(512) void kpconv_conv1_kernel(
    const float* __restrict__ pts, const float* __restrict__ sel,
    const int* __restrict__ nbr, const float* __restrict__ kp_points,
    const __half* __restrict__ kpwT_hi, const __half* __restrict__ kpwT_lo,
    const float* __restrict__ kp_sigma, const __half* __restrict__ wh,
    const float* __restrict__ bias, float* __restrict__ featmax,
    float* __restrict__ featmin, float* __restrict__ bnsum,
    float* __restrict__ bnsq) {
  const int b = blockIdx.x;
  const int tid = threadIdx.x;
  const int wave = tid >> 6, lane = tid & 63;
  const int lr = lane & 15, quad = lane >> 4;

  __shared__ __align__(16) char smem[71168];
  // phase-1 carve
  __half* As_hi = (__half*)smem;            // 112*72
  __half* As_lo = As_hi + 112 * 72;
  __half* Bs_hi = As_lo + 112 * 72;         // 128*72
  __half* Bs_lo = Bs_hi + 128 * 72;
  float* rel = (float*)(Bs_lo + 128 * 72);  // 100*4
  float* kpp = rel + 100 * 4;               // 48
  // phase-2 overlay
  __half* Hs = (__half*)smem;               // 112*136
  __half* Ws = Hs + 112 * 136;              // 128*136

  // ---- phase 1 staging
  for (int i = tid; i < 128 * 8; i += 512) {
    int row = i >> 3, seg = i & 7;
    *(float4*)&Bs_hi[row * 72 + seg * 8] =
        *(const float4*)&kpwT_hi[row * 64 + seg * 8];
    *(float4*)&Bs_lo[row * 72 + seg * 8] =
        *(const float4*)&kpwT_lo[row * 64 + seg * 8];
  }
  {
    float4 z = make_float4(0.f, 0.f, 0.f, 0.f);
    for (int i = tid; i < 112 * 8; i += 512) {
      int row = i >> 3, seg = i & 7;
      *(float4*)&As_hi[row * 72 + seg * 8] = z;
      *(float4*)&As_lo[row * 72 + seg * 8] = z;
    }
  }
  if (tid < 45) kpp[tid] = kp_points[tid];
  if (tid < 100) {
    int idx = nbr[b * KNN + tid];
    rel[tid * 4 + 0] = pts[3 * idx + 0] - sel[b * 3 + 0];
    rel[tid * 4 + 1] = pts[3 * idx + 1] - sel[b * 3 + 1];
    rel[tid * 4 + 2] = pts[3 * idx + 2] - sel[b * 3 + 2];
  }
  __syncthreads();

  const float sg = kp_sigma[0];
  const float inv2s2 = -0.5f / (sg * sg);
  for (int i = tid; i < 100 * KPN; i += 512) {
    int k = i / KPN, p = i - k * KPN;
    float rx = rel[k * 4 + 0] - kpp[p * 3 + 0];
    float ry = rel[k * 4 + 1] - kpp[p * 3 + 1];
    float rz = rel[k * 4 + 2] - kpp[p * 3 + 2];
    float w = expf(inv2s2 * (rx * rx + ry * ry + rz * rz));
#pragma unroll
    for (int c = 0; c < 3; ++c) {
      float a = rel[k * 4 + c] * w;
      __half hi = __float2half_rn(a);
      As_hi[k * 72 + p * 3 + c] = hi;
      As_lo[k * 72 + p * 3 + c] = __float2half_rn(a - __half2float(hi));
    }
  }
  __syncthreads();

  // ---- phase 1 MFMA: acc = Ahi*Bhi + Ahi*Blo + Alo*Bhi (wave owns tile w)
  f32x4 acc1[7];
#pragma unroll
  for (int m = 0; m < 7; ++m) acc1[m] = (f32x4)(0.f);
#pragma unroll
  for (int s = 0; s < 2; ++s) {
    int boff = (wave * 16 + lr) * 72 + s * 32 + quad * 8;
    half8 bhi = *(const half8*)&Bs_hi[boff];
    half8 blo = *(const half8*)&Bs_lo[boff];
#pragma unroll
    for (int m = 0; m < 7; ++m) {
      int aoff = (m * 16 + lr) * 72 + s * 32 + quad * 8;
      half8 ahi = *(const half8*)&As_hi[aoff];
      half8 alo = *(const half8*)&As_lo[aoff];
      acc1[m] = __builtin_amdgcn_mfma_f32_16x16x32_f16(ahi, bhi, acc1[m], 0, 0, 0);
      acc1[m] = __builtin_amdgcn_mfma_f32_16x16x32_f16(ahi, blo, acc1[m], 0, 0, 0);
      acc1[m] = __builtin_amdgcn_mfma_f32_16x16x32_f16(alo, bhi, acc1[m], 0, 0, 0);
    }
  }
  __syncthreads();  // As/Bs dead; safe to overlay Hs/Ws

  // ---- write h tile to LDS (rows>=100 zero: As rows were zeroed)
  {
    int col = wave * 16 + lr;
#pragma unroll
    for (int m = 0; m < 7; ++m)
#pragma unroll
      for (int r = 0; r < 4; ++r) {
        int row = m * 16 + quad * 4 + r;
        Hs[row * 136 + col] = __float2half_rn(fmaxf(acc1[m][r], 0.f));
      }
  }

  // ---- phase 2: 8 chunks of 128 output channels
  for (int c = 0; c < 8; ++c) {
    __syncthreads();  // orders Hs writes / prior-chunk Ws reads vs restage
    for (int i = tid; i < 128 * 16; i += 512) {
      int row = i >> 4, seg = i & 15;
      *(float4*)&Ws[row * 136 + seg * 8] =
          *(const float4*)&wh[(c * 128 + row) * 128 + seg * 8];
    }
    __syncthreads();

    f32x4 acc2[7];
#pragma unroll
    for (int m = 0; m < 7; ++m) acc2[m] = (f32x4)(0.f);
#pragma unroll
    for (int s = 0; s < 4; ++s) {
      half8 bfrag =
          *(const half8*)&Ws[(wave * 16 + lr) * 136 + s * 32 + quad * 8];
#pragma unroll
      for (int m = 0; m < 7; ++m) {
        half8 afrag =
            *(const half8*)&Hs[(m * 16 + lr) * 136 + s * 32 + quad * 8];
        acc2[m] = __builtin_amdgcn_mfma_f32_16x16x32_f16(afrag, bfrag,
                                                         acc2[m], 0, 0, 0);
      }
    }

    {
      int col = c * 128 + wave * 16 + lr;
      float bv = bias[col];
      float pmax = -1e30f, pmin = 1e30f, psum = 0.f, psq = 0.f;
#pragma unroll
      for (int m = 0; m < 7; ++m)
#pragma unroll
        for (int r = 0; r < 4; ++r) {
          int row = m * 16 + quad * 4 + r;
          if (row < 100) {
            float y = fmaxf(acc2[m][r] + bv, 0.f);
            pmax = fmaxf(pmax, y);
            pmin = fminf(pmin, y);
            psum += y;
            psq += y * y;
          }
        }
      pmax = fmaxf(pmax, __shfl_xor(pmax, 16));
      pmax = fmaxf(pmax, __shfl_xor(pmax, 32));
      pmin = fminf(pmin, __shfl_xor(pmin, 16));
      pmin = fminf(pmin, __shfl_xor(pmin, 32));
      psum += __shfl_xor(psum, 16);
      psum += __shfl_xor(psum, 32);
      psq += __shfl_xor(psq, 16);
      psq += __shfl_xor(psq, 32);
      if (quad == 0) {
        featmax[b * C2 + col] = pmax;
        featmin[b * C2 + col] = pmin;
        atomicAdd(&bnsum[col], psum);
        atomicAdd(&bnsq[col], psq);
      }
    }
  }
}

// ------------------------------------- fc1: BN1(max/min) + fc + relu + stats
__global__ __launch_bounds__(256) void fc1_kernel(
    const float* __restrict__ featmax, const float* __restrict__ featmin,
    const float* __restrict__ bnsum, const float* __restrict__ bnsq,
    const float* __restrict__ g, const float* __restrict__ bb,
    const float* __restrict__ w,  // [512][1024]
    const float* __restrict__ bias, float* __restrict__ yraw,
    float* __restrict__ s, float* __restrict__ sq) {
  const int r0 = blockIdx.x * 4;
  const int n0 = blockIdx.y * 64;
  const int tid = threadIdx.x;
  const int col = tid >> 2;
  const int row = tid & 3;
  __shared__ float xs[4][1028];
  __shared__ float ws[64][132];
  __shared__ float amul[C2], badd[C2];
  const float invn = 1.f / (float)(NB * KNN);
  for (int o = tid; o < C2; o += 256) {
    float m = bnsum[o] * invn;
    float v = bnsq[o] * invn - m * m;
    float a = g[o] / sqrtf(v + 1e-5f);
    amul[o] = a;
    badd[o] = bb[o] - m * a;
  }
  __syncthreads();
  for (int f = tid; f < C2; f += 256) {  // 4 rows x 256 float4
    int rr = f >> 8, kq = (f & 255) * 4;
    float4 mx = *(const float4*)&featmax[(r0 + rr) * C2 + kq];
    float4 mn = *(const float4*)&featmin[(r0 + rr) * C2 + kq];
    float4 o4;
    o4.x = (amul[kq + 0] >= 0.f ? mx.x : mn.x) * amul[kq + 0] + badd[kq + 0];
    o4.y = (amul[kq + 1] >= 0.f ? mx.y : mn.y) * amul[kq + 1] + badd[kq + 1];
    o4.z = (amul[kq + 2] >= 0.f ? mx.z : mn.z) * amul[kq + 2] + badd[kq + 2];
    o4.w = (amul[kq + 3] >= 0.f ? mx.w : mn.w) * amul[kq + 3] + badd[kq + 3];
    *(float4*)&xs[rr][kq] = o4;
  }
  float acc = 0.f;
  for (int kc = 0; kc < C2; kc += 128) {
    __syncthreads();
#pragma unroll
    for (int i = 0; i < 8; ++i) {
      int f = tid + i * 256;
      int cr = f >> 5, kq = (f & 31) * 4;
      *(float4*)&ws[cr][kq] = *(const float4*)&w[(n0 + cr) * C2 + kc + kq];
    }
    __syncthreads();
    for (int kk = 0; kk < 128; kk += 4) {
      float4 xv = *(float4*)&xs[row][kc + kk];
      float4 wv = *(float4*)&ws[col][kk];
      acc += xv.x * wv.x + xv.y * wv.y + xv.z * wv.z + xv.w * wv.w;
    }
  }
  float y = fmaxf(acc + bias[n0 + col], 0.f);
  yraw[(r0 + row) * C3 + n0 + col] = y;
  float ys = y, y2 = y * y;
  ys += __shfl_xor(ys, 1); y2 += __shfl_xor(y2, 1);
  ys += __shfl_xor(ys, 2); y2 += __shfl_xor(y2, 2);
  if (row == 0) {
    atomicAdd(&s[n0 + col], ys);
    atomicAdd(&sq[n0 + col], y2);
  }
}

// ------------------------------------- fc2: BN4 + fc + relu + stats
__global__ __launch_bounds__(256) void fc2_kernel(
    const float* __restrict__ x,  // f2raw [500][512]
    const float* __restrict__ bnsum, const float* __restrict__ bnsq,
    const float* __restrict__ g, const float* __restrict__ bb,
    const float* __restrict__ w,  // [256][512]
    const float* __restrict__ bias, float* __restrict__ yraw,
    float* __restrict__ s, float* __restrict__ sq) {
  const int r0 = blockIdx.x * 4;
  const int n0 = blockIdx.y * 64;
  const int tid = threadIdx.x;
  const int col = tid >> 2;
  const int row = tid & 3;
  __shared__ float xs[4][516];
  __shared__ float ws[64][132];
  __shared__ float amul[C3], badd[C3];
  const float invn = 1.f / (float)NB;
  for (int o = tid; o < C3; o += 256) {
    float m = bnsum[o] * invn;
    float v = bnsq[o] * invn - m * m;
    float a = g[o] / sqrtf(v + 1e-5f);
    amul[o] = a;
    badd[o] = bb[o] - m * a;
  }
  __syncthreads();
  for (int f = tid; f < C3; f += 256) {  // 4 rows x 128 float4
    int rr = f >> 7, kq = (f & 127) * 4;
    float4 xv = *(const float4*)&x[(r0 + rr) * C3 + kq];
    float4 o4;
    o4.x = xv.x * amul[kq + 0] + badd[kq + 0];
    o4.y = xv.y * amul[kq + 1] + badd[kq + 1];
    o4.z = xv.z * amul[kq + 2] + badd[kq + 2];
    o4.w = xv.w * amul[kq + 3] + badd[kq + 3];
    *(float4*)&xs[rr][kq] = o4;
  }
  float acc = 0.f;
  for (int kc = 0; kc < C3; kc += 128) {
    __syncthreads();
#pragma unroll
    for (int i = 0; i < 8; ++i) {
      int f = tid + i * 256;
      int cr = f >> 5, kq = (f & 31) * 4;
      *(float4*)&ws[cr][kq] = *(const float4*)&w[(n0 + cr) * C3 + kc + kq];
    }
    __syncthreads();
    for (int kk = 0; kk < 128; kk += 4) {
      float4 xv = *(float4*)&xs[row][kc + kk];
      float4 wv = *(float4*)&ws[col][kk];
      acc += xv.x * wv.x + xv.y * wv.y + xv.z * wv.z + xv.w * wv.w;
    }
  }
  float y = fmaxf(acc + bias[n0 + col], 0.f);
  yraw[(r0 + row) * C4 + n0 + col] = y;
  float ys = y, y2 = y * y;
  ys += __shfl_xor(ys, 1); y2 += __shfl_xor(y2, 1);
  ys += __shfl_xor(ys, 2); y2 += __shfl_xor(y2, 2);
  if (row == 0) {
    atomicAdd(&s[n0 + col], ys);
    atomicAdd(&sq[n0 + col], y2);
  }
}

// ------------------------------------------------- fc3 (BN5 fused)
__global__ __launch_bounds__(256) void fc3_kernel(
    const float* __restrict__ x,  // f3raw [500][256]
    const float* __restrict__ bnsum, const float* __restrict__ bnsq,
    const float* __restrict__ g, const float* __restrict__ bb,
    const float* __restrict__ w, const float* __restrict__ bias,
    float* __restrict__ out) {
  const int tid = threadIdx.x;
  __shared__ float pmul[C4], padd[C4];
  {
    const float invn = 1.f / (float)NB;
    float m = bnsum[tid] * invn;
    float v = bnsq[tid] * invn - m * m;
    float a = g[tid] / sqrtf(v + 1e-5f);
    pmul[tid] = a;
    padd[tid] = bb[tid] - m * a;
  }
  __syncthreads();
  int idx = blockIdx.x * 256 + tid;
  if (idx >= NB * 3) return;
  int b = idx / 3, o = idx % 3;
  float acc = 0.f;
  for (int k = 0; k < C4; ++k)
    acc += (x[b * C4 + k] * pmul[k] + padd[k]) * w[o * C4 + k];
  out[idx] = acc + bias[o];
}

// ---------------------------------------------------------------- launch
extern "C" void kernel_launch(void* const* d_in, const int* in_sizes, int n_in,
                              void* d_out, int out_size, void* d_ws,
                              size_t ws_size, hipStream_t stream) {
  const float* pts = (const float*)d_in[0];
  const float* normal = (const float*)d_in[1];
  const float* kp_points = (const float*)d_in[2];
  const float* kp_weights = (const float*)d_in[3];
  const float* kp_sigma = (const float*)d_in[4];
  const float* conv1_w = (const float*)d_in[5];
  const float* conv1_b = (const float*)d_in[6];
  const float* bn1_g = (const float*)d_in[7];
  const float* bn1_b = (const float*)d_in[8];
  const float* fc1_w = (const float*)d_in[9];
  const float* fc1_b = (const float*)d_in[10];
  const float* bn4_g = (const float*)d_in[11];
  const float* bn4_b = (const float*)d_in[12];
  const float* fc2_w = (const float*)d_in[13];
  const float* fc2_b = (const float*)d_in[14];
  const float* bn5_g = (const float*)d_in[15];
  const float* bn5_b = (const float*)d_in[16];
  const float* fc3_w = (const float*)d_in[17];
  const float* fc3_b = (const float*)d_in[18];
  const int* index = (const int*)d_in[19];
  float* out = (float*)d_out;

  char* p = (char*)d_ws;
  auto carve = [&](size_t bytes) {
    void* r = (void*)p;
    p += (bytes + 255) & ~(size_t)255;
    return r;
  };
  float* sel = (float*)carve(NB * 3 * 4);
  int* nbr = (int*)carve(NB * KNN * 4);
  __half* wh = (__half*)carve((size_t)C2 * C1 * 2);
  __half* kpwT_hi = (__half*)carve((size_t)128 * 64 * 2);
  __half* kpwT_lo = (__half*)carve((size_t)128 * 64 * 2);
  float* featmax = (float*)carve(NB * C2 * 4);
  float* featmin = (float*)carve(NB * C2 * 4);
  float* f2raw = (float*)carve(NB * C3 * 4);
  float* f3raw = (float*)carve(NB * C4 * 4);
  float* stats = (float*)carve((2 * C2 + 2 * C3 + 2 * C4) * 4);
  float* bnsum = stats;
  float* bnsq = stats + C2;
  float* s4 = stats + 2 * C2;
  float* sq4 = s4 + C3;
  float* s5 = sq4 + C3;
  float* sq5 = s5 + C4;
  // grid structures
  unsigned* cellcnt = (unsigned*)carve((size_t)NCELLS * 4);
  unsigned* cellcur = (unsigned*)carve((size_t)NCELLS * 4);
  unsigned* chunktot = (unsigned*)carve(256 * 4);
  unsigned* chunkoff = (unsigned*)carve(256 * 4);
  float4* sortedpts = (float4*)carve((size_t)NPTS * 16);

  hipMemsetAsync(stats, 0, (2 * C2 + 2 * C3 + 2 * C4) * 4, stream);
  hipMemsetAsync(cellcnt, 0, (size_t)NCELLS * 4, stream);

  prep_kernel<<<(C2 * C1 + 255) / 256, 256, 0, stream>>>(
      pts, normal, index, conv1_w, kp_weights, sel, out + NB * 3, wh, kpwT_hi,
      kpwT_lo, cellcnt);
  grid_scan1_kernel<<<256, 256, 0, stream>>>(cellcnt, cellcur, chunktot);
  grid_scan2_kernel<<<1, 256, 0, stream>>>(chunktot, chunkoff);
  grid_scan3_kernel<<<256, 256, 0, stream>>>(cellcur, chunkoff);
  grid_scatter_kernel<<<(NPTS + 255) / 256, 256, 0, stream>>>(pts, cellcur,
                                                              sortedpts);
  knn_kernel<<<NB, 256, 0, stream>>>(sortedpts, cellcnt, cellcur, sel, nbr);
  kpconv_conv1_kernel<<<NB, 512, 0, stream>>>(
      pts, sel, nbr, kp_points, kpwT_hi, kpwT_lo, kp_sigma, wh, conv1_b,
      featmax, featmin, bnsum, bnsq);
  fc1_kernel<<<dim3(125, C3 / 64), 256, 0, stream>>>(
      featmax, featmin, bnsum, bnsq, bn1_g, bn1_b, fc1_w, fc1_b, f2raw, s4,
      sq4);
  fc2_kernel<<<dim3(125, C4 / 64), 256, 0, stream>>>(
      f2raw, s4, sq4, bn4_g, bn4_b, fc2_w, fc2_b, f3raw, s5, sq5);
  fc3_kernel<<<(NB * 3 + 255) / 256, 256, 0, stream>>>(
      f3raw, s5, sq5, bn5_g, bn5_b, fc3_w, fc3_b, out);
}

// Round 7
// 266.207 us; speedup vs baseline: 1.1384x; 1.1384x over previous
//
#include <hip/hip_runtime.h>
#include <hip/hip_fp16.h>

#define NPTS 100000
#define NB 500
#define KNN 100
#define KPN 15
#define C1 128
#define C2 1024
#define C3 512
#define C4 256

// ---- L-inf kNN grid parameters
#define G 64
#define NCELLS (G * G * G)
#define GB 5.0f
#define GINVH ((float)G / (2.f * GB))  // 6.4 cells per unit
#define CAND_CAP 2048

typedef _Float16 half8 __attribute__((ext_vector_type(8)));
typedef float f32x4 __attribute__((ext_vector_type(4)));

// ------------------------------------------------- grid helpers
__device__ __forceinline__ int cell_coord(float x) {
  int c = (int)floorf((x + GB) * GINVH);
  return min(max(c, 0), G - 1);
}
__device__ __forceinline__ int cell_of(float x, float y, float z) {
  return (cell_coord(x) << 12) | (cell_coord(y) << 6) | cell_coord(z);
}

// -------------------- prep: gather + converts (incl fc1_w hi/lo) + hist
__global__ __launch_bounds__(256) void prep_kernel(
    const float* __restrict__ pts, const float* __restrict__ normal,
    const int* __restrict__ index, const float* __restrict__ w1,
    const float* __restrict__ kpw, const float* __restrict__ fc1w,
    float* __restrict__ sel, float* __restrict__ out2,
    __half* __restrict__ wh, __half* __restrict__ kpwT_hi,
    __half* __restrict__ kpwT_lo, __half* __restrict__ fwhi,
    __half* __restrict__ fwlo, unsigned* __restrict__ cnt) {
  int i = blockIdx.x * 256 + threadIdx.x;
  if (i < NB) {
    int ix = index[i];
    sel[i * 3 + 0] = pts[3 * ix + 0];
    sel[i * 3 + 1] = pts[3 * ix + 1];
    sel[i * 3 + 2] = pts[3 * ix + 2];
    out2[i * 3 + 0] = normal[3 * ix + 0];
    out2[i * 3 + 1] = normal[3 * ix + 1];
    out2[i * 3 + 2] = normal[3 * ix + 2];
  }
  if (i < C2 * C1) wh[i] = __float2half(w1[i]);
  if (i < 128 * 64) {
    int o = i >> 6, j = i & 63;
    float v = (j < 45) ? kpw[j * 128 + o] : 0.f;
    __half hi = __float2half_rn(v);
    kpwT_hi[i] = hi;
    kpwT_lo[i] = __float2half_rn(v - __half2float(hi));
  }
  if (i < C3 * C2) {
    float v = fc1w[i];
    __half hi = __float2half_rn(v);
    fwhi[i] = hi;
    fwlo[i] = __float2half_rn(v - __half2float(hi));
  }
  if (i < NPTS)
    atomicAdd(&cnt[cell_of(pts[3 * i], pts[3 * i + 1], pts[3 * i + 2])], 1u);
}

// ------------------------------------------------- grid scan (3 stages)
__global__ __launch_bounds__(256) void grid_scan1_kernel(
    const unsigned* __restrict__ cnt, unsigned* __restrict__ cursor,
    unsigned* __restrict__ chunktot) {
  const int tid = threadIdx.x;
  int base = blockIdx.x * 1024 + tid * 4;
  unsigned c0 = cnt[base], c1 = cnt[base + 1], c2 = cnt[base + 2],
           c3 = cnt[base + 3];
  unsigned tot = c0 + c1 + c2 + c3;
  __shared__ unsigned sb[256];
  sb[tid] = tot;
  __syncthreads();
  for (int off = 1; off < 256; off <<= 1) {
    unsigned add = (tid >= off) ? sb[tid - off] : 0u;
    __syncthreads();
    sb[tid] += add;
    __syncthreads();
  }
  unsigned excl = sb[tid] - tot;
  cursor[base] = excl;
  cursor[base + 1] = excl + c0;
  cursor[base + 2] = excl + c0 + c1;
  cursor[base + 3] = excl + c0 + c1 + c2;
  if (tid == 255) chunktot[blockIdx.x] = sb[255];
}

__global__ __launch_bounds__(256) void grid_scan2_kernel(
    const unsigned* __restrict__ chunktot, unsigned* __restrict__ chunkoff) {
  const int tid = threadIdx.x;
  unsigned v = chunktot[tid];
  __shared__ unsigned sb[256];
  sb[tid] = v;
  __syncthreads();
  for (int off = 1; off < 256; off <<= 1) {
    unsigned add = (tid >= off) ? sb[tid - off] : 0u;
    __syncthreads();
    sb[tid] += add;
    __syncthreads();
  }
  chunkoff[tid] = sb[tid] - v;
}

__global__ __launch_bounds__(256) void grid_scan3_kernel(
    unsigned* __restrict__ cursor, const unsigned* __restrict__ chunkoff) {
  unsigned off = chunkoff[blockIdx.x];
  int base = blockIdx.x * 1024 + threadIdx.x * 4;
#pragma unroll
  for (int j = 0; j < 4; ++j) cursor[base + j] += off;
}

// scatter: cursor turns into per-cell END offsets; begin = end - cnt
__global__ __launch_bounds__(256) void grid_scatter_kernel(
    const float* __restrict__ pts, unsigned* __restrict__ cursor,
    float4* __restrict__ sorted) {
  int i = blockIdx.x * 256 + threadIdx.x;
  if (i >= NPTS) return;
  float x = pts[3 * i], y = pts[3 * i + 1], z = pts[3 * i + 2];
  unsigned pos = atomicAdd(&cursor[cell_of(x, y, z)], 1u);
  sorted[pos] = make_float4(x, y, z, __int_as_float(i));
}

// ---------------------------------------------------------------- kNN v6
__device__ __forceinline__ unsigned linf_bits(float px, float py, float pz,
                                              float sx, float sy, float sz) {
  float dx = fabsf(px - sx), dy = fabsf(py - sy), dz = fabsf(pz - sz);
  return __float_as_uint(fmaxf(fmaxf(dx, dy), dz));
}

__global__ __launch_bounds__(256) void knn_kernel(
    const float4* __restrict__ sorted, const unsigned* __restrict__ cnt,
    const unsigned* __restrict__ cursor,  // per-cell end offsets
    const float* __restrict__ sel, int* __restrict__ nbr) {
  const int b = blockIdx.x;
  const int tid = threadIdx.x;
  __shared__ unsigned cbits[CAND_CAP];
  __shared__ int cidx[CAND_CAP];
  __shared__ unsigned hist[4096];
  __shared__ unsigned scanbuf[256];
  __shared__ int s_total, s_m, s_mc, s_chunk;
  __shared__ unsigned s_excl, s_bub;

  const float qx = sel[b * 3 + 0], qy = sel[b * 3 + 1], qz = sel[b * 3 + 2];
  const int qcx = cell_coord(qx), qcy = cell_coord(qy), qcz = cell_coord(qz);

  // ---------------- Phase A: expand cube until >=KNN (shell-incremental)
  if (tid == 0) s_total = 0;
  __syncthreads();
  int s = 1;
  int pxlo = 1, pxhi = 0, pylo = 1, pyhi = 0, pzlo = 1, pzhi = 0;  // empty
  int xlo, xhi, ylo, yhi, zlo, zhi;
  for (;;) {
    xlo = max(qcx - s, 0); xhi = min(qcx + s, G - 1);
    ylo = max(qcy - s, 0); yhi = min(qcy + s, G - 1);
    zlo = max(qcz - s, 0); zhi = min(qcz + s, G - 1);
    int nx = xhi - xlo + 1, ny = yhi - ylo + 1, nz = zhi - zlo + 1;
    int ncell = nx * ny * nz;
    unsigned local = 0;
    for (int ci = tid; ci < ncell; ci += 256) {
      int cz = ci % nz;
      int r = ci / nz;
      int cy = r % ny;
      int cx = r / ny;
      int ax = xlo + cx, ay = ylo + cy, az = zlo + cz;
      if (ax >= pxlo && ax <= pxhi && ay >= pylo && ay <= pyhi &&
          az >= pzlo && az <= pzhi)
        continue;  // interior (already counted)
      local += cnt[(ax << 12) | (ay << 6) | az];
    }
#pragma unroll
    for (int off = 32; off; off >>= 1) local += __shfl_down(local, off);
    if ((tid & 63) == 0) atomicAdd(&s_total, (int)local);
    __syncthreads();
    if (s_total >= KNN || (xlo == 0 && ylo == 0 && zlo == 0 && xhi == G - 1 &&
                           yhi == G - 1 && zhi == G - 1))
      break;
    pxlo = xlo; pxhi = xhi; pylo = ylo; pyhi = yhi; pzlo = zlo; pzhi = zhi;
    ++s;
    __syncthreads();
  }

  // ---------------- Phase B: collect cube points (per-cell batched slots)
  if (tid == 0) s_m = 0;
  __syncthreads();
  {
    int nx = xhi - xlo + 1, ny = yhi - ylo + 1, nz = zhi - zlo + 1;
    int ncell = nx * ny * nz;
    for (int ci = tid; ci < ncell; ci += 256) {
      int cz = ci % nz;
      int r = ci / nz;
      int cy = r % ny;
      int cx = r / ny;
      int cell = ((xlo + cx) << 12) | ((ylo + cy) << 6) | (zlo + cz);
      unsigned end = cursor[cell];
      unsigned beg = end - cnt[cell];
      int k = (int)(end - beg);
      if (k > 0) {
        int e0 = atomicAdd(&s_m, k);
        for (unsigned p = beg; p < end; ++p, ++e0) {
          if (e0 < CAND_CAP) {
            float4 f = sorted[p];
            cbits[e0] = linf_bits(f.x, f.y, f.z, qx, qy, qz);
            cidx[e0] = __float_as_int(f.w);
          }
        }
      }
    }
  }
  __syncthreads();
  int m = s_m < CAND_CAP ? s_m : CAND_CAP;

  // ---------------- histogram select: upper bound on 100th distance
  for (int j = tid; j < 4096; j += 256) hist[j] = 0;
  __syncthreads();
  for (int e = tid; e < m; e += 256) atomicAdd(&hist[cbits[e] >> 19], 1u);
  __syncthreads();
  unsigned csum = 0;
  {
    int c0 = tid * 16;
#pragma unroll
    for (int j = 0; j < 16; ++j) csum += hist[c0 + j];
  }
  scanbuf[tid] = csum;
  __syncthreads();
  for (int off = 1; off < 256; off <<= 1) {
    unsigned add = (tid >= off) ? scanbuf[tid - off] : 0u;
    __syncthreads();
    scanbuf[tid] += add;
    __syncthreads();
  }
  {
    unsigned incl = scanbuf[tid], excl = incl - csum;
    if (excl < KNN && KNN <= incl) {
      s_chunk = tid;
      s_excl = excl;
    }
  }
  __syncthreads();
  if (tid == 0) {
    unsigned cum = s_excl;
    int bin = s_chunk * 16;
    while (cum + hist[bin] < KNN) {
      cum += hist[bin];
      ++bin;
    }
    s_bub = (unsigned)(bin + 1) << 19;  // exclusive upper bound on bits
  }
  __syncthreads();

  // ---------------- Phase C: exact cover cube, filter bits < bound
  const unsigned bub = s_bub;
  const float dub = __uint_as_float(bub);
  if (tid == 0) s_mc = 0;
  __syncthreads();
  {
    int xlo2 = min(max((int)floorf((qx - dub + GB) * GINVH), 0), G - 1);
    int xhi2 = min(max((int)floorf((qx + dub + GB) * GINVH), 0), G - 1);
    int ylo2 = min(max((int)floorf((qy - dub + GB) * GINVH), 0), G - 1);
    int yhi2 = min(max((int)floorf((qy + dub + GB) * GINVH), 0), G - 1);
    int zlo2 = min(max((int)floorf((qz - dub + GB) * GINVH), 0), G - 1);
    int zhi2 = min(max((int)floorf((qz + dub + GB) * GINVH), 0), G - 1);
    int nx = xhi2 - xlo2 + 1, ny = yhi2 - ylo2 + 1, nz = zhi2 - zlo2 + 1;
    int ncell = nx * ny * nz;
    for (int ci = tid; ci < ncell; ci += 256) {
      int cz = ci % nz;
      int r = ci / nz;
      int cy = r % ny;
      int cx = r / ny;
      int cell = ((xlo2 + cx) << 12) | ((ylo2 + cy) << 6) | (zlo2 + cz);
      unsigned end = cursor[cell];
      unsigned beg = end - cnt[cell];
      for (unsigned p = beg; p < end; ++p) {
        float4 f = sorted[p];
        unsigned bits = linf_bits(f.x, f.y, f.z, qx, qy, qz);
        if (bits < bub) {
          int e = atomicAdd(&s_mc, 1);
          if (e < CAND_CAP) {
            cbits[e] = bits;
            cidx[e] = __float_as_int(f.w);
          }
        }
      }
    }
  }
  __syncthreads();
  int mc = s_mc < CAND_CAP ? s_mc : CAND_CAP;

  // ---------------- exact rank-select (ties by original index, stable)
  for (int c = tid; c < mc; c += 256) {
    unsigned bc = cbits[c];
    int ic = cidx[c];
    int rank = 0;
    for (int j = 0; j < mc; ++j) {
      unsigned bj = cbits[j];
      rank += (bj < bc || (bj == bc && cidx[j] < ic)) ? 1 : 0;
    }
    if (rank < KNN) nbr[b * KNN + rank] = ic;
  }
}

// ---------------------------- KPConv + conv1 FUSED (f16 MFMA, 8 waves)
__global__ __launch_bounds__(512) void kpconv_conv1_kernel(
    const float* __restrict__ pts, const float* __restrict__ sel,
    const int* __restrict__ nbr, const float* __restrict__ kp_points,
    const __half* __restrict__ kpwT_hi, const __half* __restrict__ kpwT_lo,
    const float* __restrict__ kp_sigma, const __half* __restrict__ wh,
    const float* __restrict__ bias, float* __restrict__ featmax,
    float* __restrict__ featmin, float* __restrict__ bnsum,
    float* __restrict__ bnsq) {
  const int b = blockIdx.x;
  const int tid = threadIdx.x;
  const int wave = tid >> 6, lane = tid & 63;
  const int lr = lane & 15, quad = lane >> 4;

  __shared__ __align__(16) char smem[71168];
  // phase-1 carve
  __half* As_hi = (__half*)smem;            // 112*72
  __half* As_lo = As_hi + 112 * 72;
  __half* Bs_hi = As_lo + 112 * 72;         // 128*72
  __half* Bs_lo = Bs_hi + 128 * 72;
  float* rel = (float*)(Bs_lo + 128 * 72);  // 100*4
  float* kpp = rel + 100 * 4;               // 48
  // phase-2 overlay
  __half* Hs = (__half*)smem;               // 112*136
  __half* Ws = Hs + 112 * 136;              // 128*136

  // ---- phase 1 staging
  for (int i = tid; i < 128 * 8; i += 512) {
    int row = i >> 3, seg = i & 7;
    *(float4*)&Bs_hi[row * 72 + seg * 8] =
        *(const float4*)&kpwT_hi[row * 64 + seg * 8];
    *(float4*)&Bs_lo[row * 72 + seg * 8] =
        *(const float4*)&kpwT_lo[row * 64 + seg * 8];
  }
  {
    float4 z = make_float4(0.f, 0.f, 0.f, 0.f);
    for (int i = tid; i < 112 * 8; i += 512) {
      int row = i >> 3, seg = i & 7;
      *(float4*)&As_hi[row * 72 + seg * 8] = z;
      *(float4*)&As_lo[row * 72 + seg * 8] = z;
    }
  }
  if (tid < 45) kpp[tid] = kp_points[tid];
  if (tid < 100) {
    int idx = nbr[b * KNN + tid];
    rel[tid * 4 + 0] = pts[3 * idx + 0] - sel[b * 3 + 0];
    rel[tid * 4 + 1] = pts[3 * idx + 1] - sel[b * 3 + 1];
    rel[tid * 4 + 2] = pts[3 * idx + 2] - sel[b * 3 + 2];
  }
  __syncthreads();

  const float sg = kp_sigma[0];
  const float inv2s2 = -0.5f / (sg * sg);
  for (int i = tid; i < 100 * KPN; i += 512) {
    int k = i / KPN, p = i - k * KPN;
    float rx = rel[k * 4 + 0] - kpp[p * 3 + 0];
    float ry = rel[k * 4 + 1] - kpp[p * 3 + 1];
    float rz = rel[k * 4 + 2] - kpp[p * 3 + 2];
    float w = expf(inv2s2 * (rx * rx + ry * ry + rz * rz));
#pragma unroll
    for (int c = 0; c < 3; ++c) {
      float a = rel[k * 4 + c] * w;
      __half hi = __float2half_rn(a);
      As_hi[k * 72 + p * 3 + c] = hi;
      As_lo[k * 72 + p * 3 + c] = __float2half_rn(a - __half2float(hi));
    }
  }
  __syncthreads();

  // ---- phase 1 MFMA: acc = Ahi*Bhi + Ahi*Blo + Alo*Bhi (wave owns tile w)
  f32x4 acc1[7];
#pragma unroll
  for (int m = 0; m < 7; ++m) acc1[m] = (f32x4)(0.f);
#pragma unroll
  for (int s = 0; s < 2; ++s) {
    int boff = (wave * 16 + lr) * 72 + s * 32 + quad * 8;
    half8 bhi = *(const half8*)&Bs_hi[boff];
    half8 blo = *(const half8*)&Bs_lo[boff];
#pragma unroll
    for (int m = 0; m < 7; ++m) {
      int aoff = (m * 16 + lr) * 72 + s * 32 + quad * 8;
      half8 ahi = *(const half8*)&As_hi[aoff];
      half8 alo = *(const half8*)&As_lo[aoff];
      acc1[m] = __builtin_amdgcn_mfma_f32_16x16x32_f16(ahi, bhi, acc1[m], 0, 0, 0);
      acc1[m] = __builtin_amdgcn_mfma_f32_16x16x32_f16(ahi, blo, acc1[m], 0, 0, 0);
      acc1[m] = __builtin_amdgcn_mfma_f32_16x16x32_f16(alo, bhi, acc1[m], 0, 0, 0);
    }
  }
  __syncthreads();  // As/Bs dead; safe to overlay Hs/Ws

  // ---- write h tile to LDS (rows>=100 zero: As rows were zeroed)
  {
    int col = wave * 16 + lr;
#pragma unroll
    for (int m = 0; m < 7; ++m)
#pragma unroll
      for (int r = 0; r < 4; ++r) {
        int row = m * 16 + quad * 4 + r;
        Hs[row * 136 + col] = __float2half_rn(fmaxf(acc1[m][r], 0.f));
      }
  }

  // ---- phase 2: 8 chunks of 128 output channels
  for (int c = 0; c < 8; ++c) {
    __syncthreads();
    for (int i = tid; i < 128 * 16; i += 512) {
      int row = i >> 4, seg = i & 15;
      *(float4*)&Ws[row * 136 + seg * 8] =
          *(const float4*)&wh[(c * 128 + row) * 128 + seg * 8];
    }
    __syncthreads();

    f32x4 acc2[7];
#pragma unroll
    for (int m = 0; m < 7; ++m) acc2[m] = (f32x4)(0.f);
#pragma unroll
    for (int s = 0; s < 4; ++s) {
      half8 bfrag =
          *(const half8*)&Ws[(wave * 16 + lr) * 136 + s * 32 + quad * 8];
#pragma unroll
      for (int m = 0; m < 7; ++m) {
        half8 afrag =
            *(const half8*)&Hs[(m * 16 + lr) * 136 + s * 32 + quad * 8];
        acc2[m] = __builtin_amdgcn_mfma_f32_16x16x32_f16(afrag, bfrag,
                                                         acc2[m], 0, 0, 0);
      }
    }

    {
      int col = c * 128 + wave * 16 + lr;
      float bv = bias[col];
      float pmax = -1e30f, pmin = 1e30f, psum = 0.f, psq = 0.f;
#pragma unroll
      for (int m = 0; m < 7; ++m)
#pragma unroll
        for (int r = 0; r < 4; ++r) {
          int row = m * 16 + quad * 4 + r;
          if (row < 100) {
            float y = fmaxf(acc2[m][r] + bv, 0.f);
            pmax = fmaxf(pmax, y);
            pmin = fminf(pmin, y);
            psum += y;
            psq += y * y;
          }
        }
      pmax = fmaxf(pmax, __shfl_xor(pmax, 16));
      pmax = fmaxf(pmax, __shfl_xor(pmax, 32));
      pmin = fminf(pmin, __shfl_xor(pmin, 16));
      pmin = fminf(pmin, __shfl_xor(pmin, 32));
      psum += __shfl_xor(psum, 16);
      psum += __shfl_xor(psum, 32);
      psq += __shfl_xor(psq, 16);
      psq += __shfl_xor(psq, 32);
      if (quad == 0) {
        featmax[b * C2 + col] = pmax;
        featmin[b * C2 + col] = pmin;
        atomicAdd(&bnsum[col], psum);
        atomicAdd(&bnsq[col], psq);
      }
    }
  }
}

// --------------------------- BN1 finalize -> feat1 as f16 hi/lo pair
__global__ __launch_bounds__(256) void bn1half_kernel(
    const float* __restrict__ featmax, const float* __restrict__ featmin,
    const float* __restrict__ bnsum, const float* __restrict__ bnsq,
    const float* __restrict__ g, const float* __restrict__ bb,
    __half* __restrict__ Xhi, __half* __restrict__ Xlo) {
  int idx = blockIdx.x * 256 + threadIdx.x;
  if (idx >= NB * C2) return;
  int o = idx & (C2 - 1);
  const float invn = 1.f / (float)(NB * KNN);
  float m = bnsum[o] * invn;
  float v = bnsq[o] * invn - m * m;
  float a = g[o] / sqrtf(v + 1e-5f);
  float x = (a >= 0.f) ? featmax[idx] : featmin[idx];  // max of monotone map
  float y = (x - m) * a + bb[o];
  __half hi = __float2half_rn(y);
  Xhi[idx] = hi;
  Xlo[idx] = __float2half_rn(y - __half2float(hi));
}

// --------------------------- fc1 via MFMA (hi/lo X and W, 3 passes)
// f2raw[500][512] = relu(X[500][1024] x W^T + b); per-col sum/sq stats.
// grid (8 row-tiles of 64, 8 col-chunks of 64), 256 thr (4 waves).
__global__ __launch_bounds__(256) void fc1_mfma_kernel(
    const __half* __restrict__ Xhi, const __half* __restrict__ Xlo,
    const __half* __restrict__ Whi, const __half* __restrict__ Wlo,
    const float* __restrict__ bias, float* __restrict__ yraw,
    float* __restrict__ s, float* __restrict__ sq) {
  const int r0 = blockIdx.x * 64;
  const int n0 = blockIdx.y * 64;
  const int tid = threadIdx.x;
  const int wave = tid >> 6, lane = tid & 63;
  const int lr = lane & 15, quad = lane >> 4;
  __shared__ __half Xs_hi[64 * 72], Xs_lo[64 * 72];
  __shared__ __half Ws_hi[64 * 72], Ws_lo[64 * 72];

  f32x4 acc[4];
#pragma unroll
  for (int m = 0; m < 4; ++m) acc[m] = (f32x4)(0.f);

  for (int kc = 0; kc < C2; kc += 64) {
    __syncthreads();  // protect prior-iteration reads
    for (int i = tid; i < 64 * 8; i += 256) {
      int row = i >> 3, seg = i & 7;
      int gr = r0 + row;
      float4 vhi = make_float4(0.f, 0.f, 0.f, 0.f), vlo = vhi;
      if (gr < NB) {
        vhi = *(const float4*)&Xhi[gr * C2 + kc + seg * 8];
        vlo = *(const float4*)&Xlo[gr * C2 + kc + seg * 8];
      }
      *(float4*)&Xs_hi[row * 72 + seg * 8] = vhi;
      *(float4*)&Xs_lo[row * 72 + seg * 8] = vlo;
      *(float4*)&Ws_hi[row * 72 + seg * 8] =
          *(const float4*)&Whi[(n0 + row) * C2 + kc + seg * 8];
      *(float4*)&Ws_lo[row * 72 + seg * 8] =
          *(const float4*)&Wlo[(n0 + row) * C2 + kc + seg * 8];
    }
    __syncthreads();

#pragma unroll
    for (int s2 = 0; s2 < 2; ++s2) {
      int boff = (wave * 16 + lr) * 72 + s2 * 32 + quad * 8;
      half8 bhi = *(const half8*)&Ws_hi[boff];
      half8 blo = *(const half8*)&Ws_lo[boff];
#pragma unroll
      for (int m = 0; m < 4; ++m) {
        int aoff = (m * 16 + lr) * 72 + s2 * 32 + quad * 8;
        half8 ahi = *(const half8*)&Xs_hi[aoff];
        half8 alo = *(const half8*)&Xs_lo[aoff];
        acc[m] = __builtin_amdgcn_mfma_f32_16x16x32_f16(ahi, bhi, acc[m], 0, 0, 0);
        acc[m] = __builtin_amdgcn_mfma_f32_16x16x32_f16(ahi, blo, acc[m], 0, 0, 0);
        acc[m] = __builtin_amdgcn_mfma_f32_16x16x32_f16(alo, bhi, acc[m], 0, 0, 0);
      }
    }
  }

  // epilogue: relu + write + stats
  {
    int col = n0 + wave * 16 + lr;
    float bv = bias[col];
    float psum = 0.f, psq = 0.f;
#pragma unroll
    for (int m = 0; m < 4; ++m)
#pragma unroll
      for (int r = 0; r < 4; ++r) {
        int row = r0 + m * 16 + quad * 4 + r;
        if (row < NB) {
          float y = fmaxf(acc[m][r] + bv, 0.f);
          yraw[row * C3 + col] = y;
          psum += y;
          psq += y * y;
        }
      }
    psum += __shfl_xor(psum, 16);
    psum += __shfl_xor(psum, 32);
    psq += __shfl_xor(psq, 16);
    psq += __shfl_xor(psq, 32);
    if (quad == 0) {
      atomicAdd(&s[col], psum);
      atomicAdd(&sq[col], psq);
    }
  }
}

// ------------------------------------- fc2: BN4 + fc + relu + stats
__global__ __launch_bounds__(256) void fc2_kernel(
    const float* __restrict__ x,  // f2raw [500][512]
    const float* __restrict__ bnsum, const float* __restrict__ bnsq,
    const float* __restrict__ g, const float* __restrict__ bb,
    const float* __restrict__ w,  // [256][512]
    const float* __restrict__ bias, float* __restrict__ yraw,
    float* __restrict__ s, float* __restrict__ sq) {
  const int r0 = blockIdx.x * 4;
  const int n0 = blockIdx.y * 64;
  const int tid = threadIdx.x;
  const int col = tid >> 2;
  const int row = tid & 3;
  __shared__ float xs[4][516];
  __shared__ float ws[64][132];
  __shared__ float amul[C3], badd[C3];
  const float invn = 1.f / (float)NB;
  for (int o = tid; o < C3; o += 256) {
    float m = bnsum[o] * invn;
    float v = bnsq[o] * invn - m * m;
    float a = g[o] / sqrtf(v + 1e-5f);
    amul[o] = a;
    badd[o] = bb[o] - m * a;
  }
  __syncthreads();
  for (int f = tid; f < C3; f += 256) {  // 4 rows x 128 float4
    int rr = f >> 7, kq = (f & 127) * 4;
    float4 xv = *(const float4*)&x[(r0 + rr) * C3 + kq];
    float4 o4;
    o4.x = xv.x * amul[kq + 0] + badd[kq + 0];
    o4.y = xv.y * amul[kq + 1] + badd[kq + 1];
    o4.z = xv.z * amul[kq + 2] + badd[kq + 2];
    o4.w = xv.w * amul[kq + 3] + badd[kq + 3];
    *(float4*)&xs[rr][kq] = o4;
  }
  float acc = 0.f;
  for (int kc = 0; kc < C3; kc += 128) {
    __syncthreads();
#pragma unroll
    for (int i = 0; i < 8; ++i) {
      int f = tid + i * 256;
      int cr = f >> 5, kq = (f & 31) * 4;
      *(float4*)&ws[cr][kq] = *(const float4*)&w[(n0 + cr) * C3 + kc + kq];
    }
    __syncthreads();
    for (int kk = 0; kk < 128; kk += 4) {
      float4 xv = *(float4*)&xs[row][kc + kk];
      float4 wv = *(float4*)&ws[col][kk];
      acc += xv.x * wv.x + xv.y * wv.y + xv.z * wv.z + xv.w * wv.w;
    }
  }
  float y = fmaxf(acc + bias[n0 + col], 0.f);
  yraw[(r0 + row) * C4 + n0 + col] = y;
  float ys = y, y2 = y * y;
  ys += __shfl_xor(ys, 1); y2 += __shfl_xor(y2, 1);
  ys += __shfl_xor(ys, 2); y2 += __shfl_xor(y2, 2);
  if (row == 0) {
    atomicAdd(&s[n0 + col], ys);
    atomicAdd(&sq[n0 + col], y2);
  }
}

// ------------------------------------------------- fc3 (BN5 fused)
__global__ __launch_bounds__(256) void fc3_kernel(
    const float* __restrict__ x,  // f3raw [500][256]
    const float* __restrict__ bnsum, const float* __restrict__ bnsq,
    const float* __restrict__ g, const float* __restrict__ bb,
    const float* __restrict__ w, const float* __restrict__ bias,
    float* __restrict__ out) {
  const int tid = threadIdx.x;
  __shared__ float pmul[C4], padd[C4];
  {
    const float invn = 1.f / (float)NB;
    float m = bnsum[tid] * invn;
    float v = bnsq[tid] * invn - m * m;
    float a = g[tid] / sqrtf(v + 1e-5f);
    pmul[tid] = a;
    padd[tid] = bb[tid] - m * a;
  }
  __syncthreads();
  int idx = blockIdx.x * 256 + tid;
  if (idx >= NB * 3) return;
  int b = idx / 3, o = idx % 3;
  float acc = 0.f;
  for (int k = 0; k < C4; ++k)
    acc += (x[b * C4 + k] * pmul[k] + padd[k]) * w[o * C4 + k];
  out[idx] = acc + bias[o];
}

// ---------------------------------------------------------------- launch
extern "C" void kernel_launch(void* const* d_in, const int* in_sizes, int n_in,
                              void* d_out, int out_size, void* d_ws,
                              size_t ws_size, hipStream_t stream) {
  const float* pts = (const float*)d_in[0];
  const float* normal = (const float*)d_in[1];
  const float* kp_points = (const float*)d_in[2];
  const float* kp_weights = (const float*)d_in[3];
  const float* kp_sigma = (const float*)d_in[4];
  const float* conv1_w = (const float*)d_in[5];
  const float* conv1_b = (const float*)d_in[6];
  const float* bn1_g = (const float*)d_in[7];
  const float* bn1_b = (const float*)d_in[8];
  const float* fc1_w = (const float*)d_in[9];
  const float* fc1_b = (const float*)d_in[10];
  const float* bn4_g = (const float*)d_in[11];
  const float* bn4_b = (const float*)d_in[12];
  const float* fc2_w = (const float*)d_in[13];
  const float* fc2_b = (const float*)d_in[14];
  const float* bn5_g = (const float*)d_in[15];
  const float* bn5_b = (const float*)d_in[16];
  const float* fc3_w = (const float*)d_in[17];
  const float* fc3_b = (const float*)d_in[18];
  const int* index = (const int*)d_in[19];
  float* out = (float*)d_out;

  char* p = (char*)d_ws;
  auto carve = [&](size_t bytes) {
    void* r = (void*)p;
    p += (bytes + 255) & ~(size_t)255;
    return r;
  };
  float* sel = (float*)carve(NB * 3 * 4);
  int* nbr = (int*)carve(NB * KNN * 4);
  __half* wh = (__half*)carve((size_t)C2 * C1 * 2);
  __half* kpwT_hi = (__half*)carve((size_t)128 * 64 * 2);
  __half* kpwT_lo = (__half*)carve((size_t)128 * 64 * 2);
  __half* fwhi = (__half*)carve((size_t)C3 * C2 * 2);
  __half* fwlo = (__half*)carve((size_t)C3 * C2 * 2);
  __half* Xhi = (__half*)carve((size_t)NB * C2 * 2);
  __half* Xlo = (__half*)carve((size_t)NB * C2 * 2);
  float* featmax = (float*)carve(NB * C2 * 4);
  float* featmin = (float*)carve(NB * C2 * 4);
  float* f2raw = (float*)carve(NB * C3 * 4);
  float* f3raw = (float*)carve(NB * C4 * 4);
  float* stats = (float*)carve((2 * C2 + 2 * C3 + 2 * C4) * 4);
  float* bnsum = stats;
  float* bnsq = stats + C2;
  float* s4 = stats + 2 * C2;
  float* sq4 = s4 + C3;
  float* s5 = sq4 + C3;
  float* sq5 = s5 + C4;
  // grid structures
  unsigned* cellcnt = (unsigned*)carve((size_t)NCELLS * 4);
  unsigned* cellcur = (unsigned*)carve((size_t)NCELLS * 4);
  unsigned* chunktot = (unsigned*)carve(256 * 4);
  unsigned* chunkoff = (unsigned*)carve(256 * 4);
  float4* sortedpts = (float4*)carve((size_t)NPTS * 16);

  hipMemsetAsync(stats, 0, (2 * C2 + 2 * C3 + 2 * C4) * 4, stream);
  hipMemsetAsync(cellcnt, 0, (size_t)NCELLS * 4, stream);

  prep_kernel<<<(C3 * C2 + 255) / 256, 256, 0, stream>>>(
      pts, normal, index, conv1_w, kp_weights, fc1_w, sel, out + NB * 3, wh,
      kpwT_hi, kpwT_lo, fwhi, fwlo, cellcnt);
  grid_scan1_kernel<<<256, 256, 0, stream>>>(cellcnt, cellcur, chunktot);
  grid_scan2_kernel<<<1, 256, 0, stream>>>(chunktot, chunkoff);
  grid_scan3_kernel<<<256, 256, 0, stream>>>(cellcur, chunkoff);
  grid_scatter_kernel<<<(NPTS + 255) / 256, 256, 0, stream>>>(pts, cellcur,
                                                              sortedpts);
  knn_kernel<<<NB, 256, 0, stream>>>(sortedpts, cellcnt, cellcur, sel, nbr);
  kpconv_conv1_kernel<<<NB, 512, 0, stream>>>(
      pts, sel, nbr, kp_points, kpwT_hi, kpwT_lo, kp_sigma, wh, conv1_b,
      featmax, featmin, bnsum, bnsq);
  bn1half_kernel<<<(NB * C2 + 255) / 256, 256, 0, stream>>>(
      featmax, featmin, bnsum, bnsq, bn1_g, bn1_b, Xhi, Xlo);
  fc1_mfma_kernel<<<dim3(8, 8), 256, 0, stream>>>(Xhi, Xlo, fwhi, fwlo, fc1_b,
                                                  f2raw, s4, sq4);
  fc2_kernel<<<dim3(125, C4 / 64), 256, 0, stream>>>(
      f2raw, s4, sq4, bn4_g, bn4_b, fc2_w, fc2_b, f3raw, s5, sq5);
  fc3_kernel<<<(NB * 3 + 255) / 256, 256, 0, stream>>>(
      f3raw, s5, sq5, bn5_g, bn5_b, fc3_w, fc3_b, out);
}

// Round 8
// 255.568 us; speedup vs baseline: 1.1858x; 1.0416x over previous
//
#include <hip/hip_runtime.h>
#include <hip/hip_fp16.h>

#define NPTS 100000
#define NB 500
#define KNN 100
#define KPN 15
#define C1 128
#define C2 1024
#define C3 512
#define C4 256

// ---- L-inf kNN grid parameters
#define G 64
#define NCELLS (G * G * G)
#define GB 5.0f
#define GINVH ((float)G / (2.f * GB))  // 6.4 cells per unit
#define CAND_CAP 2048

typedef _Float16 half8 __attribute__((ext_vector_type(8)));
typedef float f32x4 __attribute__((ext_vector_type(4)));

// ------------------------------------------------- grid helpers
__device__ __forceinline__ int cell_coord(float x) {
  int c = (int)floorf((x + GB) * GINVH);
  return min(max(c, 0), G - 1);
}
__device__ __forceinline__ int cell_of(float x, float y, float z) {
  return (cell_coord(x) << 12) | (cell_coord(y) << 6) | cell_coord(z);
}

// -------------------- prep: gather + converts (incl fc1_w hi/lo) + hist
__global__ __launch_bounds__(256) void prep_kernel(
    const float* __restrict__ pts, const float* __restrict__ normal,
    const int* __restrict__ index, const float* __restrict__ w1,
    const float* __restrict__ kpw, const float* __restrict__ fc1w,
    float* __restrict__ sel, float* __restrict__ out2,
    __half* __restrict__ wh, __half* __restrict__ kpwT_hi,
    __half* __restrict__ kpwT_lo, __half* __restrict__ fwhi,
    __half* __restrict__ fwlo, unsigned* __restrict__ cnt) {
  int i = blockIdx.x * 256 + threadIdx.x;
  if (i < NB) {
    int ix = index[i];
    sel[i * 3 + 0] = pts[3 * ix + 0];
    sel[i * 3 + 1] = pts[3 * ix + 1];
    sel[i * 3 + 2] = pts[3 * ix + 2];
    out2[i * 3 + 0] = normal[3 * ix + 0];
    out2[i * 3 + 1] = normal[3 * ix + 1];
    out2[i * 3 + 2] = normal[3 * ix + 2];
  }
  if (i < C2 * C1) wh[i] = __float2half(w1[i]);
  if (i < 128 * 64) {
    int o = i >> 6, j = i & 63;
    float v = (j < 45) ? kpw[j * 128 + o] : 0.f;
    __half hi = __float2half_rn(v);
    kpwT_hi[i] = hi;
    kpwT_lo[i] = __float2half_rn(v - __half2float(hi));
  }
  if (i < C3 * C2) {
    float v = fc1w[i];
    __half hi = __float2half_rn(v);
    fwhi[i] = hi;
    fwlo[i] = __float2half_rn(v - __half2float(hi));
  }
  if (i < NPTS)
    atomicAdd(&cnt[cell_of(pts[3 * i], pts[3 * i + 1], pts[3 * i + 2])], 1u);
}

// ------------------------------------------------- grid scan (3 stages)
__global__ __launch_bounds__(256) void grid_scan1_kernel(
    const unsigned* __restrict__ cnt, unsigned* __restrict__ cursor,
    unsigned* __restrict__ chunktot) {
  const int tid = threadIdx.x;
  int base = blockIdx.x * 1024 + tid * 4;
  unsigned c0 = cnt[base], c1 = cnt[base + 1], c2 = cnt[base + 2],
           c3 = cnt[base + 3];
  unsigned tot = c0 + c1 + c2 + c3;
  __shared__ unsigned sb[256];
  sb[tid] = tot;
  __syncthreads();
  for (int off = 1; off < 256; off <<= 1) {
    unsigned add = (tid >= off) ? sb[tid - off] : 0u;
    __syncthreads();
    sb[tid] += add;
    __syncthreads();
  }
  unsigned excl = sb[tid] - tot;
  cursor[base] = excl;
  cursor[base + 1] = excl + c0;
  cursor[base + 2] = excl + c0 + c1;
  cursor[base + 3] = excl + c0 + c1 + c2;
  if (tid == 255) chunktot[blockIdx.x] = sb[255];
}

__global__ __launch_bounds__(256) void grid_scan2_kernel(
    const unsigned* __restrict__ chunktot, unsigned* __restrict__ chunkoff) {
  const int tid = threadIdx.x;
  unsigned v = chunktot[tid];
  __shared__ unsigned sb[256];
  sb[tid] = v;
  __syncthreads();
  for (int off = 1; off < 256; off <<= 1) {
    unsigned add = (tid >= off) ? sb[tid - off] : 0u;
    __syncthreads();
    sb[tid] += add;
    __syncthreads();
  }
  chunkoff[tid] = sb[tid] - v;
}

__global__ __launch_bounds__(256) void grid_scan3_kernel(
    unsigned* __restrict__ cursor, const unsigned* __restrict__ chunkoff) {
  unsigned off = chunkoff[blockIdx.x];
  int base = blockIdx.x * 1024 + threadIdx.x * 4;
#pragma unroll
  for (int j = 0; j < 4; ++j) cursor[base + j] += off;
}

// scatter: cursor turns into per-cell END offsets; begin = end - cnt
__global__ __launch_bounds__(256) void grid_scatter_kernel(
    const float* __restrict__ pts, unsigned* __restrict__ cursor,
    float4* __restrict__ sorted) {
  int i = blockIdx.x * 256 + threadIdx.x;
  if (i >= NPTS) return;
  float x = pts[3 * i], y = pts[3 * i + 1], z = pts[3 * i + 2];
  unsigned pos = atomicAdd(&cursor[cell_of(x, y, z)], 1u);
  sorted[pos] = make_float4(x, y, z, __int_as_float(i));
}

// ---------------------------------------------------------------- kNN v6
__device__ __forceinline__ unsigned linf_bits(float px, float py, float pz,
                                              float sx, float sy, float sz) {
  float dx = fabsf(px - sx), dy = fabsf(py - sy), dz = fabsf(pz - sz);
  return __float_as_uint(fmaxf(fmaxf(dx, dy), dz));
}

__global__ __launch_bounds__(256) void knn_kernel(
    const float4* __restrict__ sorted, const unsigned* __restrict__ cnt,
    const unsigned* __restrict__ cursor,  // per-cell end offsets
    const float* __restrict__ sel, int* __restrict__ nbr) {
  const int b = blockIdx.x;
  const int tid = threadIdx.x;
  __shared__ unsigned cbits[CAND_CAP];
  __shared__ int cidx[CAND_CAP];
  __shared__ unsigned hist[4096];
  __shared__ unsigned scanbuf[256];
  __shared__ int s_total, s_m, s_mc, s_chunk;
  __shared__ unsigned s_excl, s_bub;

  const float qx = sel[b * 3 + 0], qy = sel[b * 3 + 1], qz = sel[b * 3 + 2];
  const int qcx = cell_coord(qx), qcy = cell_coord(qy), qcz = cell_coord(qz);

  // ---------------- Phase A: expand cube until >=KNN (shell-incremental)
  if (tid == 0) s_total = 0;
  __syncthreads();
  int s = 1;
  int pxlo = 1, pxhi = 0, pylo = 1, pyhi = 0, pzlo = 1, pzhi = 0;  // empty
  int xlo, xhi, ylo, yhi, zlo, zhi;
  for (;;) {
    xlo = max(qcx - s, 0); xhi = min(qcx + s, G - 1);
    ylo = max(qcy - s, 0); yhi = min(qcy + s, G - 1);
    zlo = max(qcz - s, 0); zhi = min(qcz + s, G - 1);
    int nx = xhi - xlo + 1, ny = yhi - ylo + 1, nz = zhi - zlo + 1;
    int ncell = nx * ny * nz;
    unsigned local = 0;
    for (int ci = tid; ci < ncell; ci += 256) {
      int cz = ci % nz;
      int r = ci / nz;
      int cy = r % ny;
      int cx = r / ny;
      int ax = xlo + cx, ay = ylo + cy, az = zlo + cz;
      if (ax >= pxlo && ax <= pxhi && ay >= pylo && ay <= pyhi &&
          az >= pzlo && az <= pzhi)
        continue;  // interior (already counted)
      local += cnt[(ax << 12) | (ay << 6) | az];
    }
#pragma unroll
    for (int off = 32; off; off >>= 1) local += __shfl_down(local, off);
    if ((tid & 63) == 0) atomicAdd(&s_total, (int)local);
    __syncthreads();
    if (s_total >= KNN || (xlo == 0 && ylo == 0 && zlo == 0 && xhi == G - 1 &&
                           yhi == G - 1 && zhi == G - 1))
      break;
    pxlo = xlo; pxhi = xhi; pylo = ylo; pyhi = yhi; pzlo = zlo; pzhi = zhi;
    ++s;
    __syncthreads();
  }

  // ---------------- Phase B: collect cube points (per-cell batched slots)
  if (tid == 0) s_m = 0;
  __syncthreads();
  {
    int nx = xhi - xlo + 1, ny = yhi - ylo + 1, nz = zhi - zlo + 1;
    int ncell = nx * ny * nz;
    for (int ci = tid; ci < ncell; ci += 256) {
      int cz = ci % nz;
      int r = ci / nz;
      int cy = r % ny;
      int cx = r / ny;
      int cell = ((xlo + cx) << 12) | ((ylo + cy) << 6) | (zlo + cz);
      unsigned end = cursor[cell];
      unsigned beg = end - cnt[cell];
      int k = (int)(end - beg);
      if (k > 0) {
        int e0 = atomicAdd(&s_m, k);
        for (unsigned p = beg; p < end; ++p, ++e0) {
          if (e0 < CAND_CAP) {
            float4 f = sorted[p];
            cbits[e0] = linf_bits(f.x, f.y, f.z, qx, qy, qz);
            cidx[e0] = __float_as_int(f.w);
          }
        }
      }
    }
  }
  __syncthreads();
  int m = s_m < CAND_CAP ? s_m : CAND_CAP;

  // ---------------- histogram select: upper bound on 100th distance
  for (int j = tid; j < 4096; j += 256) hist[j] = 0;
  __syncthreads();
  for (int e = tid; e < m; e += 256) atomicAdd(&hist[cbits[e] >> 19], 1u);
  __syncthreads();
  unsigned csum = 0;
  {
    int c0 = tid * 16;
#pragma unroll
    for (int j = 0; j < 16; ++j) csum += hist[c0 + j];
  }
  scanbuf[tid] = csum;
  __syncthreads();
  for (int off = 1; off < 256; off <<= 1) {
    unsigned add = (tid >= off) ? scanbuf[tid - off] : 0u;
    __syncthreads();
    scanbuf[tid] += add;
    __syncthreads();
  }
  {
    unsigned incl = scanbuf[tid], excl = incl - csum;
    if (excl < KNN && KNN <= incl) {
      s_chunk = tid;
      s_excl = excl;
    }
  }
  __syncthreads();
  if (tid == 0) {
    unsigned cum = s_excl;
    int bin = s_chunk * 16;
    while (cum + hist[bin] < KNN) {
      cum += hist[bin];
      ++bin;
    }
    s_bub = (unsigned)(bin + 1) << 19;  // exclusive upper bound on bits
  }
  __syncthreads();

  // ---------------- Phase C: exact cover cube, filter bits < bound
  const unsigned bub = s_bub;
  const float dub = __uint_as_float(bub);
  if (tid == 0) s_mc = 0;
  __syncthreads();
  {
    int xlo2 = min(max((int)floorf((qx - dub + GB) * GINVH), 0), G - 1);
    int xhi2 = min(max((int)floorf((qx + dub + GB) * GINVH), 0), G - 1);
    int ylo2 = min(max((int)floorf((qy - dub + GB) * GINVH), 0), G - 1);
    int yhi2 = min(max((int)floorf((qy + dub + GB) * GINVH), 0), G - 1);
    int zlo2 = min(max((int)floorf((qz - dub + GB) * GINVH), 0), G - 1);
    int zhi2 = min(max((int)floorf((qz + dub + GB) * GINVH), 0), G - 1);
    int nx = xhi2 - xlo2 + 1, ny = yhi2 - ylo2 + 1, nz = zhi2 - zlo2 + 1;
    int ncell = nx * ny * nz;
    for (int ci = tid; ci < ncell; ci += 256) {
      int cz = ci % nz;
      int r = ci / nz;
      int cy = r % ny;
      int cx = r / ny;
      int cell = ((xlo2 + cx) << 12) | ((ylo2 + cy) << 6) | (zlo2 + cz);
      unsigned end = cursor[cell];
      unsigned beg = end - cnt[cell];
      for (unsigned p = beg; p < end; ++p) {
        float4 f = sorted[p];
        unsigned bits = linf_bits(f.x, f.y, f.z, qx, qy, qz);
        if (bits < bub) {
          int e = atomicAdd(&s_mc, 1);
          if (e < CAND_CAP) {
            cbits[e] = bits;
            cidx[e] = __float_as_int(f.w);
          }
        }
      }
    }
  }
  __syncthreads();
  int mc = s_mc < CAND_CAP ? s_mc : CAND_CAP;

  // ---------------- exact rank-select (ties by original index, stable)
  for (int c = tid; c < mc; c += 256) {
    unsigned bc = cbits[c];
    int ic = cidx[c];
    int rank = 0;
    for (int j = 0; j < mc; ++j) {
      unsigned bj = cbits[j];
      rank += (bj < bc || (bj == bc && cidx[j] < ic)) ? 1 : 0;
    }
    if (rank < KNN) nbr[b * KNN + rank] = ic;
  }
}

// ---------------------------- KPConv + conv1 FUSED (f16 MFMA, 8 waves)
// v3: phase-2 is LDS-free. After phase 1, each wave caches all 28 Hs
// A-fragments in registers (112 VGPRs, read from LDS once instead of
// once per chunk) and streams its B col-tile directly from L2-resident
// wh (4x16B coalesced loads/chunk, one-chunk-ahead register prefetch).
// No Ws staging, no barriers in the chunk loop. VGPR ~200 -> 2 waves/SIMD
// (__launch_bounds__(512,2)); the old version was LDS-pipe-bound
// (~30us of ds_read_b128 + 4.7M conflict cycles), not occupancy-bound.
__global__ __launch_bounds__(512, 2) void kpconv_conv1_kernel(
    const float* __restrict__ pts, const float* __restrict__ sel,
    const int* __restrict__ nbr, const float* __restrict__ kp_points,
    const __half* __restrict__ kpwT_hi, const __half* __restrict__ kpwT_lo,
    const float* __restrict__ kp_sigma, const __half* __restrict__ wh,
    const float* __restrict__ bias, float* __restrict__ featmax,
    float* __restrict__ featmin, float* __restrict__ bnsum,
    float* __restrict__ bnsq) {
  const int b = blockIdx.x;
  const int tid = threadIdx.x;
  const int wave = tid >> 6, lane = tid & 63;
  const int lr = lane & 15, quad = lane >> 4;

  __shared__ __align__(16) char smem[71168];
  // phase-1 carve
  __half* As_hi = (__half*)smem;            // 112*72
  __half* As_lo = As_hi + 112 * 72;
  __half* Bs_hi = As_lo + 112 * 72;         // 128*72
  __half* Bs_lo = Bs_hi + 128 * 72;
  float* rel = (float*)(Bs_lo + 128 * 72);  // 100*4
  float* kpp = rel + 100 * 4;               // 48
  // phase-2 overlay: Hs only
  __half* Hs = (__half*)smem;               // 112*136

  // ---- phase 1 staging
  for (int i = tid; i < 128 * 8; i += 512) {
    int row = i >> 3, seg = i & 7;
    *(float4*)&Bs_hi[row * 72 + seg * 8] =
        *(const float4*)&kpwT_hi[row * 64 + seg * 8];
    *(float4*)&Bs_lo[row * 72 + seg * 8] =
        *(const float4*)&kpwT_lo[row * 64 + seg * 8];
  }
  {
    float4 z = make_float4(0.f, 0.f, 0.f, 0.f);
    for (int i = tid; i < 112 * 8; i += 512) {
      int row = i >> 3, seg = i & 7;
      *(float4*)&As_hi[row * 72 + seg * 8] = z;
      *(float4*)&As_lo[row * 72 + seg * 8] = z;
    }
  }
  if (tid < 45) kpp[tid] = kp_points[tid];
  if (tid < 100) {
    int idx = nbr[b * KNN + tid];
    rel[tid * 4 + 0] = pts[3 * idx + 0] - sel[b * 3 + 0];
    rel[tid * 4 + 1] = pts[3 * idx + 1] - sel[b * 3 + 1];
    rel[tid * 4 + 2] = pts[3 * idx + 2] - sel[b * 3 + 2];
  }
  __syncthreads();

  const float sg = kp_sigma[0];
  const float inv2s2 = -0.5f / (sg * sg);
  for (int i = tid; i < 100 * KPN; i += 512) {
    int k = i / KPN, p = i - k * KPN;
    float rx = rel[k * 4 + 0] - kpp[p * 3 + 0];
    float ry = rel[k * 4 + 1] - kpp[p * 3 + 1];
    float rz = rel[k * 4 + 2] - kpp[p * 3 + 2];
    float w = expf(inv2s2 * (rx * rx + ry * ry + rz * rz));
#pragma unroll
    for (int c = 0; c < 3; ++c) {
      float a = rel[k * 4 + c] * w;
      __half hi = __float2half_rn(a);
      As_hi[k * 72 + p * 3 + c] = hi;
      As_lo[k * 72 + p * 3 + c] = __float2half_rn(a - __half2float(hi));
    }
  }
  __syncthreads();

  // ---- phase 1 MFMA: acc = Ahi*Bhi + Ahi*Blo + Alo*Bhi (wave owns tile w)
  f32x4 acc1[7];
#pragma unroll
  for (int m = 0; m < 7; ++m) acc1[m] = (f32x4)(0.f);
#pragma unroll
  for (int s = 0; s < 2; ++s) {
    int boff = (wave * 16 + lr) * 72 + s * 32 + quad * 8;
    half8 bhi = *(const half8*)&Bs_hi[boff];
    half8 blo = *(const half8*)&Bs_lo[boff];
#pragma unroll
    for (int m = 0; m < 7; ++m) {
      int aoff = (m * 16 + lr) * 72 + s * 32 + quad * 8;
      half8 ahi = *(const half8*)&As_hi[aoff];
      half8 alo = *(const half8*)&As_lo[aoff];
      acc1[m] = __builtin_amdgcn_mfma_f32_16x16x32_f16(ahi, bhi, acc1[m], 0, 0, 0);
      acc1[m] = __builtin_amdgcn_mfma_f32_16x16x32_f16(ahi, blo, acc1[m], 0, 0, 0);
      acc1[m] = __builtin_amdgcn_mfma_f32_16x16x32_f16(alo, bhi, acc1[m], 0, 0, 0);
    }
  }
  __syncthreads();  // As/Bs dead; safe to overlay Hs

  // ---- write h tile to LDS (rows>=100 zero: As rows were zeroed)
  {
    int col = wave * 16 + lr;
#pragma unroll
    for (int m = 0; m < 7; ++m)
#pragma unroll
      for (int r = 0; r < 4; ++r) {
        int row = m * 16 + quad * 4 + r;
        Hs[row * 136 + col] = __float2half_rn(fmaxf(acc1[m][r], 0.f));
      }
  }
  __syncthreads();  // Hs complete (cross-wave cols)

  // ---- cache all A-fragments in registers (one-time LDS read)
  half8 afr[4][7];
#pragma unroll
  for (int s = 0; s < 4; ++s)
#pragma unroll
    for (int m = 0; m < 7; ++m)
      afr[s][m] = *(const half8*)&Hs[(m * 16 + lr) * 136 + s * 32 + quad * 8];

  // ---- phase 2: 8 chunks, B direct from L2 wh, register prefetch
  const int wrow = wave * 16 + lr;  // row within chunk
  half8 bcur[4];
#pragma unroll
  for (int s = 0; s < 4; ++s)
    bcur[s] = *(const half8*)&wh[wrow * 128 + s * 32 + quad * 8];

  for (int c = 0; c < 8; ++c) {
    half8 bnxt[4];
    if (c + 1 < 8) {
#pragma unroll
      for (int s = 0; s < 4; ++s)
        bnxt[s] = *(const half8*)&wh[((c + 1) * 128 + wrow) * 128 + s * 32 +
                                     quad * 8];
    }

    f32x4 acc2[7];
#pragma unroll
    for (int m = 0; m < 7; ++m) acc2[m] = (f32x4)(0.f);
#pragma unroll
    for (int s = 0; s < 4; ++s)
#pragma unroll
      for (int m = 0; m < 7; ++m)
        acc2[m] = __builtin_amdgcn_mfma_f32_16x16x32_f16(afr[s][m], bcur[s],
                                                         acc2[m], 0, 0, 0);

    {
      int col = c * 128 + wrow;
      float bv = bias[col];
      float pmax = -1e30f, pmin = 1e30f, psum = 0.f, psq = 0.f;
#pragma unroll
      for (int m = 0; m < 7; ++m)
#pragma unroll
        for (int r = 0; r < 4; ++r) {
          int row = m * 16 + quad * 4 + r;
          if (row < 100) {
            float y = fmaxf(acc2[m][r] + bv, 0.f);
            pmax = fmaxf(pmax, y);
            pmin = fminf(pmin, y);
            psum += y;
            psq += y * y;
          }
        }
      pmax = fmaxf(pmax, __shfl_xor(pmax, 16));
      pmax = fmaxf(pmax, __shfl_xor(pmax, 32));
      pmin = fminf(pmin, __shfl_xor(pmin, 16));
      pmin = fminf(pmin, __shfl_xor(pmin, 32));
      psum += __shfl_xor(psum, 16);
      psum += __shfl_xor(psum, 32);
      psq += __shfl_xor(psq, 16);
      psq += __shfl_xor(psq, 32);
      if (quad == 0) {
        featmax[b * C2 + col] = pmax;
        featmin[b * C2 + col] = pmin;
        atomicAdd(&bnsum[col], psum);
        atomicAdd(&bnsq[col], psq);
      }
    }
#pragma unroll
    for (int s = 0; s < 4; ++s) bcur[s] = bnxt[s];
  }
}

// --------------------------- BN1 finalize -> feat1 as f16 hi/lo pair
__global__ __launch_bounds__(256) void bn1half_kernel(
    const float* __restrict__ featmax, const float* __restrict__ featmin,
    const float* __restrict__ bnsum, const float* __restrict__ bnsq,
    const float* __restrict__ g, const float* __restrict__ bb,
    __half* __restrict__ Xhi, __half* __restrict__ Xlo) {
  int idx = blockIdx.x * 256 + threadIdx.x;
  if (idx >= NB * C2) return;
  int o = idx & (C2 - 1);
  const float invn = 1.f / (float)(NB * KNN);
  float m = bnsum[o] * invn;
  float v = bnsq[o] * invn - m * m;
  float a = g[o] / sqrtf(v + 1e-5f);
  float x = (a >= 0.f) ? featmax[idx] : featmin[idx];  // max of monotone map
  float y = (x - m) * a + bb[o];
  __half hi = __float2half_rn(y);
  Xhi[idx] = hi;
  Xlo[idx] = __float2half_rn(y - __half2float(hi));
}

// --------------------------- fc1 via MFMA (hi/lo X and W, 3 passes)
__global__ __launch_bounds__(256) void fc1_mfma_kernel(
    const __half* __restrict__ Xhi, const __half* __restrict__ Xlo,
    const __half* __restrict__ Whi, const __half* __restrict__ Wlo,
    const float* __restrict__ bias, float* __restrict__ yraw,
    float* __restrict__ s, float* __restrict__ sq) {
  const int r0 = blockIdx.x * 64;
  const int n0 = blockIdx.y * 64;
  const int tid = threadIdx.x;
  const int wave = tid >> 6, lane = tid & 63;
  const int lr = lane & 15, quad = lane >> 4;
  __shared__ __half Xs_hi[64 * 72], Xs_lo[64 * 72];
  __shared__ __half Ws_hi[64 * 72], Ws_lo[64 * 72];

  f32x4 acc[4];
#pragma unroll
  for (int m = 0; m < 4; ++m) acc[m] = (f32x4)(0.f);

  for (int kc = 0; kc < C2; kc += 64) {
    __syncthreads();  // protect prior-iteration reads
    for (int i = tid; i < 64 * 8; i += 256) {
      int row = i >> 3, seg = i & 7;
      int gr = r0 + row;
      float4 vhi = make_float4(0.f, 0.f, 0.f, 0.f), vlo = vhi;
      if (gr < NB) {
        vhi = *(const float4*)&Xhi[gr * C2 + kc + seg * 8];
        vlo = *(const float4*)&Xlo[gr * C2 + kc + seg * 8];
      }
      *(float4*)&Xs_hi[row * 72 + seg * 8] = vhi;
      *(float4*)&Xs_lo[row * 72 + seg * 8] = vlo;
      *(float4*)&Ws_hi[row * 72 + seg * 8] =
          *(const float4*)&Whi[(n0 + row) * C2 + kc + seg * 8];
      *(float4*)&Ws_lo[row * 72 + seg * 8] =
          *(const float4*)&Wlo[(n0 + row) * C2 + kc + seg * 8];
    }
    __syncthreads();

#pragma unroll
    for (int s2 = 0; s2 < 2; ++s2) {
      int boff = (wave * 16 + lr) * 72 + s2 * 32 + quad * 8;
      half8 bhi = *(const half8*)&Ws_hi[boff];
      half8 blo = *(const half8*)&Ws_lo[boff];
#pragma unroll
      for (int m = 0; m < 4; ++m) {
        int aoff = (m * 16 + lr) * 72 + s2 * 32 + quad * 8;
        half8 ahi = *(const half8*)&Xs_hi[aoff];
        half8 alo = *(const half8*)&Xs_lo[aoff];
        acc[m] = __builtin_amdgcn_mfma_f32_16x16x32_f16(ahi, bhi, acc[m], 0, 0, 0);
        acc[m] = __builtin_amdgcn_mfma_f32_16x16x32_f16(ahi, blo, acc[m], 0, 0, 0);
        acc[m] = __builtin_amdgcn_mfma_f32_16x16x32_f16(alo, bhi, acc[m], 0, 0, 0);
      }
    }
  }

  // epilogue: relu + write + stats
  {
    int col = n0 + wave * 16 + lr;
    float bv = bias[col];
    float psum = 0.f, psq = 0.f;
#pragma unroll
    for (int m = 0; m < 4; ++m)
#pragma unroll
      for (int r = 0; r < 4; ++r) {
        int row = r0 + m * 16 + quad * 4 + r;
        if (row < NB) {
          float y = fmaxf(acc[m][r] + bv, 0.f);
          yraw[row * C3 + col] = y;
          psum += y;
          psq += y * y;
        }
      }
    psum += __shfl_xor(psum, 16);
    psum += __shfl_xor(psum, 32);
    psq += __shfl_xor(psq, 16);
    psq += __shfl_xor(psq, 32);
    if (quad == 0) {
      atomicAdd(&s[col], psum);
      atomicAdd(&sq[col], psq);
    }
  }
}

// ------------------------------------- fc2: BN4 + fc + relu + stats
__global__ __launch_bounds__(256) void fc2_kernel(
    const float* __restrict__ x,  // f2raw [500][512]
    const float* __restrict__ bnsum, const float* __restrict__ bnsq,
    const float* __restrict__ g, const float* __restrict__ bb,
    const float* __restrict__ w,  // [256][512]
    const float* __restrict__ bias, float* __restrict__ yraw,
    float* __restrict__ s, float* __restrict__ sq) {
  const int r0 = blockIdx.x * 4;
  const int n0 = blockIdx.y * 64;
  const int tid = threadIdx.x;
  const int col = tid >> 2;
  const int row = tid & 3;
  __shared__ float xs[4][516];
  __shared__ float ws[64][132];
  __shared__ float amul[C3], badd[C3];
  const float invn = 1.f / (float)NB;
  for (int o = tid; o < C3; o += 256) {
    float m = bnsum[o] * invn;
    float v = bnsq[o] * invn - m * m;
    float a = g[o] / sqrtf(v + 1e-5f);
    amul[o] = a;
    badd[o] = bb[o] - m * a;
  }
  __syncthreads();
  for (int f = tid; f < C3; f += 256) {  // 4 rows x 128 float4
    int rr = f >> 7, kq = (f & 127) * 4;
    float4 xv = *(const float4*)&x[(r0 + rr) * C3 + kq];
    float4 o4;
    o4.x = xv.x * amul[kq + 0] + badd[kq + 0];
    o4.y = xv.y * amul[kq + 1] + badd[kq + 1];
    o4.z = xv.z * amul[kq + 2] + badd[kq + 2];
    o4.w = xv.w * amul[kq + 3] + badd[kq + 3];
    *(float4*)&xs[rr][kq] = o4;
  }
  float acc = 0.f;
  for (int kc = 0; kc < C3; kc += 128) {
    __syncthreads();
#pragma unroll
    for (int i = 0; i < 8; ++i) {
      int f = tid + i * 256;
      int cr = f >> 5, kq = (f & 31) * 4;
      *(float4*)&ws[cr][kq] = *(const float4*)&w[(n0 + cr) * C3 + kc + kq];
    }
    __syncthreads();
    for (int kk = 0; kk < 128; kk += 4) {
      float4 xv = *(float4*)&xs[row][kc + kk];
      float4 wv = *(float4*)&ws[col][kk];
      acc += xv.x * wv.x + xv.y * wv.y + xv.z * wv.z + xv.w * wv.w;
    }
  }
  float y = fmaxf(acc + bias[n0 + col], 0.f);
  yraw[(r0 + row) * C4 + n0 + col] = y;
  float ys = y, y2 = y * y;
  ys += __shfl_xor(ys, 1); y2 += __shfl_xor(y2, 1);
  ys += __shfl_xor(ys, 2); y2 += __shfl_xor(y2, 2);
  if (row == 0) {
    atomicAdd(&s[n0 + col], ys);
    atomicAdd(&sq[n0 + col], y2);
  }
}

// ------------------------------------------------- fc3 (BN5 fused)
__global__ __launch_bounds__(256) void fc3_kernel(
    const float* __restrict__ x,  // f3raw [500][256]
    const float* __restrict__ bnsum, const float* __restrict__ bnsq,
    const float* __restrict__ g, const float* __restrict__ bb,
    const float* __restrict__ w, const float* __restrict__ bias,
    float* __restrict__ out) {
  const int tid = threadIdx.x;
  __shared__ float pmul[C4], padd[C4];
  {
    const float invn = 1.f / (float)NB;
    float m = bnsum[tid] * invn;
    float v = bnsq[tid] * invn - m * m;
    float a = g[tid] / sqrtf(v + 1e-5f);
    pmul[tid] = a;
    padd[tid] = bb[tid] - m * a;
  }
  __syncthreads();
  int idx = blockIdx.x * 256 + tid;
  if (idx >= NB * 3) return;
  int b = idx / 3, o = idx % 3;
  float acc = 0.f;
  for (int k = 0; k < C4; ++k)
    acc += (x[b * C4 + k] * pmul[k] + padd[k]) * w[o * C4 + k];
  out[idx] = acc + bias[o];
}

// ---------------------------------------------------------------- launch
extern "C" void kernel_launch(void* const* d_in, const int* in_sizes, int n_in,
                              void* d_out, int out_size, void* d_ws,
                              size_t ws_size, hipStream_t stream) {
  const float* pts = (const float*)d_in[0];
  const float* normal = (const float*)d_in[1];
  const float* kp_points = (const float*)d_in[2];
  const float* kp_weights = (const float*)d_in[3];
  const float* kp_sigma = (const float*)d_in[4];
  const float* conv1_w = (const float*)d_in[5];
  const float* conv1_b = (const float*)d_in[6];
  const float* bn1_g = (const float*)d_in[7];
  const float* bn1_b = (const float*)d_in[8];
  const float* fc1_w = (const float*)d_in[9];
  const float* fc1_b = (const float*)d_in[10];
  const float* bn4_g = (const float*)d_in[11];
  const float* bn4_b = (const float*)d_in[12];
  const float* fc2_w = (const float*)d_in[13];
  const float* fc2_b = (const float*)d_in[14];
  const float* bn5_g = (const float*)d_in[15];
  const float* bn5_b = (const float*)d_in[16];
  const float* fc3_w = (const float*)d_in[17];
  const float* fc3_b = (const float*)d_in[18];
  const int* index = (const int*)d_in[19];
  float* out = (float*)d_out;

  char* p = (char*)d_ws;
  auto carve = [&](size_t bytes) {
    void* r = (void*)p;
    p += (bytes + 255) & ~(size_t)255;
    return r;
  };
  float* sel = (float*)carve(NB * 3 * 4);
  int* nbr = (int*)carve(NB * KNN * 4);
  __half* wh = (__half*)carve((size_t)C2 * C1 * 2);
  __half* kpwT_hi = (__half*)carve((size_t)128 * 64 * 2);
  __half* kpwT_lo = (__half*)carve((size_t)128 * 64 * 2);
  __half* fwhi = (__half*)carve((size_t)C3 * C2 * 2);
  __half* fwlo = (__half*)carve((size_t)C3 * C2 * 2);
  __half* Xhi = (__half*)carve((size_t)NB * C2 * 2);
  __half* Xlo = (__half*)carve((size_t)NB * C2 * 2);
  float* featmax = (float*)carve(NB * C2 * 4);
  float* featmin = (float*)carve(NB * C2 * 4);
  float* f2raw = (float*)carve(NB * C3 * 4);
  float* f3raw = (float*)carve(NB * C4 * 4);
  float* stats = (float*)carve((2 * C2 + 2 * C3 + 2 * C4) * 4);
  float* bnsum = stats;
  float* bnsq = stats + C2;
  float* s4 = stats + 2 * C2;
  float* sq4 = s4 + C3;
  float* s5 = sq4 + C3;
  float* sq5 = s5 + C4;
  // grid structures
  unsigned* cellcnt = (unsigned*)carve((size_t)NCELLS * 4);
  unsigned* cellcur = (unsigned*)carve((size_t)NCELLS * 4);
  unsigned* chunktot = (unsigned*)carve(256 * 4);
  unsigned* chunkoff = (unsigned*)carve(256 * 4);
  float4* sortedpts = (float4*)carve((size_t)NPTS * 16);

  hipMemsetAsync(stats, 0, (2 * C2 + 2 * C3 + 2 * C4) * 4, stream);
  hipMemsetAsync(cellcnt, 0, (size_t)NCELLS * 4, stream);

  prep_kernel<<<(C3 * C2 + 255) / 256, 256, 0, stream>>>(
      pts, normal, index, conv1_w, kp_weights, fc1_w, sel, out + NB * 3, wh,
      kpwT_hi, kpwT_lo, fwhi, fwlo, cellcnt);
  grid_scan1_kernel<<<256, 256, 0, stream>>>(cellcnt, cellcur, chunktot);
  grid_scan2_kernel<<<1, 256, 0, stream>>>(chunktot, chunkoff);
  grid_scan3_kernel<<<256, 256, 0, stream>>>(cellcur, chunkoff);
  grid_scatter_kernel<<<(NPTS + 255) / 256, 256, 0, stream>>>(pts, cellcur,
                                                              sortedpts);
  knn_kernel<<<NB, 256, 0, stream>>>(sortedpts, cellcnt, cellcur, sel, nbr);
  kpconv_conv1_kernel<<<NB, 512, 0, stream>>>(
      pts, sel, nbr, kp_points, kpwT_hi, kpwT_lo, kp_sigma, wh, conv1_b,
      featmax, featmin, bnsum, bnsq);
  bn1half_kernel<<<(NB * C2 + 255) / 256, 256, 0, stream>>>(
      featmax, featmin, bnsum, bnsq, bn1_g, bn1_b, Xhi, Xlo);
  fc1_mfma_kernel<<<dim3(8, 8), 256, 0, stream>>>(Xhi, Xlo, fwhi, fwlo, fc1_b,
                                                  f2raw, s4, sq4);
  fc2_kernel<<<dim3(125, C4 / 64), 256, 0, stream>>>(
      f2raw, s4, sq4, bn4_g, bn4_b, fc2_w, fc2_b, f3raw, s5, sq5);
  fc3_kernel<<<(NB * 3 + 255) / 256, 256, 0, stream>>>(
      f3raw, s5, sq5, bn5_g, bn5_b, fc3_w, fc3_b, out);
}